// Round 1
// baseline (674.568 us; speedup 1.0000x reference)
//
#include <hip/hip_runtime.h>
#include <hip/hip_bf16.h>
#include <stdint.h>

// MultiHeadAttention_79714593013958 — cosine-normalized MHA, MI355X bf16 MFMA pipeline.
// Shapes hardcoded: bs=2, qlen=2048, dim=2048, heads=16, dph=128.
//
// Pipeline:
//  1) cast5:      X, Wq, Wk, Wv, Wo  f32 -> bf16 (contiguous in ws)
//  2) gemm_bt x3: Q/K/V = X @ W^T + b   (bf16 out)
//  3) norm_qk:    per-(row,head) L2 normalize Q (xscale) and K, in place
//  4) transpose_v: V[4096][2048] -> Vt[32 bh][128 d][2048 s]
//  5) attn:       per (b,h,128-row q-tile): S=QK^T (mfma), w=mask?exp(s):0
//                 (scores bounded by attention_scale => no max needed),
//                 accumulate den and O=sum w*V via mfma, ctx = O/den (bf16)
//  6) gemm_bt:    out = ctx @ Wo^T + bo (f32 out)

typedef __attribute__((ext_vector_type(8))) short bf16x8;
typedef __attribute__((ext_vector_type(4))) float f32x4;
typedef __attribute__((ext_vector_type(8))) unsigned short u16x8;

#define XN 8388608L   // 2*2048*2048
#define WN 4194304L   // 2048*2048  (= 2^22)

__device__ __forceinline__ float bf2f(unsigned short u) {
  union { unsigned int i; float f; } v; v.i = ((unsigned int)u) << 16; return v.f;
}
__device__ __forceinline__ unsigned short f2bf(float f) {
  union { float f; unsigned int i; } u; u.f = f;
  unsigned int r = u.i + 0x7FFFu + ((u.i >> 16) & 1u);  // RNE, inputs are finite
  return (unsigned short)(r >> 16);
}

__device__ __forceinline__ void gload_lds16(const void* g, void* l) {
  __builtin_amdgcn_global_load_lds((__attribute__((address_space(1))) void*)g,
                                   (__attribute__((address_space(3))) void*)l,
                                   16, 0, 0);
}

// ---------------- 1) f32 -> bf16 cast of X + 4 weights ----------------
__global__ __launch_bounds__(256) void cast5_kernel(
    const float* __restrict__ x,  const float* __restrict__ w0,
    const float* __restrict__ w1, const float* __restrict__ w2,
    const float* __restrict__ w3, unsigned short* __restrict__ dst)
{
  const long total8 = (XN + 4 * WN) >> 3;  // 3145728 chunks of 8 elems
  for (long i = (long)blockIdx.x * blockDim.x + threadIdx.x; i < total8;
       i += (long)gridDim.x * blockDim.x) {
    long e = i << 3;
    const float* src; long off;
    if (e < XN) { src = x; off = e; }
    else {
      long r = e - XN;
      int wi = (int)(r >> 22);
      off = r & (WN - 1);
      src = (wi == 0) ? w0 : (wi == 1) ? w1 : (wi == 2) ? w2 : w3;
    }
    const float4* p = (const float4*)(src + off);
    float4 a = p[0], b = p[1];
    u16x8 o;
    o[0] = f2bf(a.x); o[1] = f2bf(a.y); o[2] = f2bf(a.z); o[3] = f2bf(a.w);
    o[4] = f2bf(b.x); o[5] = f2bf(b.y); o[6] = f2bf(b.z); o[7] = f2bf(b.w);
    *(u16x8*)(dst + e) = o;
  }
}

// ---------------- 2/6) C[M,N] = A[M,K] * B[N,K]^T + bias, m97-style ----------------
template<int OUT_BF16>
__global__ __launch_bounds__(256) void gemm_bt(
    const unsigned short* __restrict__ A, const unsigned short* __restrict__ B,
    const float* __restrict__ bias, void* __restrict__ Cout,
    int M, int N, int K)
{
  __shared__ unsigned short As[128 * 32];
  __shared__ unsigned short Bs[128 * 32];
  const int t    = threadIdx.x;
  const int lane = t & 63;
  const int w    = t >> 6;
  const int wr   = w >> 1, wc = w & 1;
  const int l15  = lane & 15;
  const int koff = (lane >> 4) * 8;
  const int lg4  = (lane >> 4) * 4;

  const long Kl = K;
  const unsigned short* Ag0 = A + (long)(blockIdx.y * 128 + (t >> 2)) * Kl + (t & 3) * 8;
  const unsigned short* Bg0 = B + (long)(blockIdx.x * 128 + (t >> 2)) * Kl + (t & 3) * 8;
  unsigned short* Asl = As + t * 8;
  unsigned short* Bsl = Bs + t * 8;

  f32x4 acc[4][4];
  const f32x4 zero = {0.f, 0.f, 0.f, 0.f};
  #pragma unroll
  for (int m = 0; m < 4; m++) {
    #pragma unroll
    for (int n = 0; n < 4; n++) acc[m][n] = zero;
  }

  const int nK = K >> 5;
  for (int kk = 0; kk < nK; kk++) {
    const long ko = (long)kk * 32;
    gload_lds16(Ag0 + ko,            Asl);
    gload_lds16(Ag0 + 64 * Kl + ko,  Asl + 2048);
    gload_lds16(Bg0 + ko,            Bsl);
    gload_lds16(Bg0 + 64 * Kl + ko,  Bsl + 2048);
    __syncthreads();
    bf16x8 af[4], bfr[4];
    #pragma unroll
    for (int m = 0; m < 4; m++)
      af[m] = *(const bf16x8*)&As[(wr * 64 + m * 16 + l15) * 32 + koff];
    #pragma unroll
    for (int n = 0; n < 4; n++)
      bfr[n] = *(const bf16x8*)&Bs[(wc * 64 + n * 16 + l15) * 32 + koff];
    #pragma unroll
    for (int m = 0; m < 4; m++) {
      #pragma unroll
      for (int n = 0; n < 4; n++)
        acc[m][n] = __builtin_amdgcn_mfma_f32_16x16x32_bf16(af[m], bfr[n], acc[m][n], 0, 0, 0);
    }
    __syncthreads();
  }

  #pragma unroll
  for (int m = 0; m < 4; m++) {
    const int row = blockIdx.y * 128 + wr * 64 + m * 16 + lg4;
    #pragma unroll
    for (int n = 0; n < 4; n++) {
      const int col = blockIdx.x * 128 + wc * 64 + n * 16 + l15;
      const float bv = bias[col];
      #pragma unroll
      for (int r = 0; r < 4; r++) {
        float v = acc[m][n][r] + bv;
        if (OUT_BF16) ((unsigned short*)Cout)[(long)(row + r) * N + col] = f2bf(v);
        else          ((float*)Cout)[(long)(row + r) * N + col] = v;
      }
    }
  }
}

// ---------------- 3) per-(row,head) L2 norm of Q (x scale) and K ----------------
__global__ __launch_bounds__(256) void norm_qk(unsigned short* __restrict__ Q,
                                               unsigned short* __restrict__ Kb,
                                               const float* __restrict__ scale_p)
{
  const int w = threadIdx.x >> 6, lane = threadIdx.x & 63;
  const long id = (long)blockIdx.x * 4 + w;       // 0 .. 131071
  const int isK = id >= 65536;
  const long p = isK ? id - 65536 : id;           // row*16 + head
  unsigned short* base = (isK ? Kb : Q) + (p >> 4) * 2048 + (p & 15) * 128 + lane * 2;
  unsigned int v = *(const unsigned int*)base;
  float x0 = bf2f((unsigned short)(v & 0xffffu));
  float x1 = bf2f((unsigned short)(v >> 16));
  float ss = x0 * x0 + x1 * x1;
  ss += __shfl_xor(ss, 1);  ss += __shfl_xor(ss, 2);  ss += __shfl_xor(ss, 4);
  ss += __shfl_xor(ss, 8);  ss += __shfl_xor(ss, 16); ss += __shfl_xor(ss, 32);
  float inv = rsqrtf(fmaxf(ss, 1e-24f));
  if (!isK) inv *= *scale_p;
  unsigned int o = (unsigned int)f2bf(x0 * inv) | ((unsigned int)f2bf(x1 * inv) << 16);
  *(unsigned int*)base = o;
}

// ---------------- 4) V[b*2048+s][h*128+d] -> Vt[bh][d][s] ----------------
__global__ __launch_bounds__(256) void transpose_v(const unsigned short* __restrict__ V,
                                                   unsigned short* __restrict__ Vt)
{
  __shared__ unsigned short tile[64][66];
  const int bh = blockIdx.z;
  const int b = bh >> 4, h = bh & 15;
  const int s0 = blockIdx.x * 64;
  const int d0 = blockIdx.y * 64;
  const int t = threadIdx.x;
  const int c = t & 63, r4 = t >> 6;
  #pragma unroll
  for (int i = 0; i < 16; i++) {
    int r = r4 + i * 4;
    tile[r][c] = V[(long)(b * 2048 + s0 + r) * 2048 + h * 128 + d0 + c];
  }
  __syncthreads();
  #pragma unroll
  for (int i = 0; i < 16; i++) {
    int dd = r4 + i * 4;
    Vt[((long)bh * 128 + d0 + dd) * 2048 + s0 + c] = tile[c][dd];
  }
}

// ---------------- 5) fused cosine attention ----------------
// grid: (16 q-tiles, 32 bh). 4 waves/block, each wave owns 32 q-rows.
__global__ __launch_bounds__(256) void attn_kernel(
    const unsigned short* __restrict__ Q,   // normalized*scale
    const unsigned short* __restrict__ Kb,  // normalized
    const unsigned short* __restrict__ Vt,  // [bh][128][2048]
    const int* __restrict__ mask,           // [2][2048]
    unsigned short* __restrict__ ctx)       // [4096][2048] bf16
{
  __shared__ unsigned short Pl[4][32][72];  // per-wave P tile, padded stride 72
  const int bh = blockIdx.y;
  const int b = bh >> 4, h = bh & 15;
  const int t = threadIdx.x, w = t >> 6, lane = t & 63;
  const int l15 = lane & 15, lg = lane >> 4, koff = lg * 8;
  const int qrow0 = blockIdx.x * 128 + w * 32;

  // Q fragments in registers: rows qrow0 + m*16 + l15, d = dk*32 + koff + 0..7
  bf16x8 aq[2][4];
  #pragma unroll
  for (int m = 0; m < 2; m++) {
    #pragma unroll
    for (int dk = 0; dk < 4; dk++)
      aq[m][dk] = *(const bf16x8*)&Q[(long)(b * 2048 + qrow0 + m * 16 + l15) * 2048
                                     + h * 128 + dk * 32 + koff];
  }

  f32x4 o[2][8];
  float den[2][4];
  const f32x4 zero = {0.f, 0.f, 0.f, 0.f};
  #pragma unroll
  for (int m = 0; m < 2; m++) {
    #pragma unroll
    for (int df = 0; df < 8; df++) o[m][df] = zero;
    #pragma unroll
    for (int r = 0; r < 4; r++) den[m][r] = 0.f;
  }

  const unsigned short* Kbase = Kb + (long)b * 2048 * 2048 + h * 128;
  const unsigned short* Vbase = Vt + (long)bh * 128 * 2048;
  const int* mbase = mask + b * 2048;

  for (int kt = 0; kt < 32; kt++) {
    const int k0 = kt * 64;
    // ---- S = Q K^T for 64 keys ----
    f32x4 s[2][4];
    #pragma unroll
    for (int m = 0; m < 2; m++) {
      #pragma unroll
      for (int n = 0; n < 4; n++) s[m][n] = zero;
    }
    #pragma unroll
    for (int n = 0; n < 4; n++) {
      bf16x8 bk[4];
      #pragma unroll
      for (int dk = 0; dk < 4; dk++)
        bk[dk] = *(const bf16x8*)&Kbase[(long)(k0 + n * 16 + l15) * 2048 + dk * 32 + koff];
      #pragma unroll
      for (int dk = 0; dk < 4; dk++) {
        s[0][n] = __builtin_amdgcn_mfma_f32_16x16x32_bf16(aq[0][dk], bk[dk], s[0][n], 0, 0, 0);
        s[1][n] = __builtin_amdgcn_mfma_f32_16x16x32_bf16(aq[1][dk], bk[dk], s[1][n], 0, 0, 0);
      }
    }
    // ---- w = mask ? exp(s) : 0 ; den += w ; P -> LDS (bf16) ----
    // scores bounded by attention_scale (cosine attn) => no max subtraction
    #pragma unroll
    for (int n = 0; n < 4; n++) {
      const bool mk = mbase[k0 + n * 16 + l15] != 0;
      #pragma unroll
      for (int m = 0; m < 2; m++) {
        #pragma unroll
        for (int r = 0; r < 4; r++) {
          float e = mk ? exp2f(s[m][n][r] * 1.44269504088896f) : 0.f;
          den[m][r] += e;
          Pl[w][m * 16 + lg * 4 + r][n * 16 + l15] = f2bf(e);
        }
      }
    }
    // ---- O += P V  (A-frag from wave-private LDS, B-frag from Vt global) ----
    #pragma unroll
    for (int kk = 0; kk < 2; kk++) {
      bf16x8 ap0 = *(const bf16x8*)&Pl[w][l15][kk * 32 + koff];
      bf16x8 ap1 = *(const bf16x8*)&Pl[w][16 + l15][kk * 32 + koff];
      #pragma unroll
      for (int df = 0; df < 8; df++) {
        bf16x8 bv = *(const bf16x8*)&Vbase[(long)(df * 16 + l15) * 2048 + k0 + kk * 32 + koff];
        o[0][df] = __builtin_amdgcn_mfma_f32_16x16x32_bf16(ap0, bv, o[0][df], 0, 0, 0);
        o[1][df] = __builtin_amdgcn_mfma_f32_16x16x32_bf16(ap1, bv, o[1][df], 0, 0, 0);
      }
    }
  }

  // ---- den row-reduce across the 16-lane col groups, then ctx = O/den ----
  #pragma unroll
  for (int m = 0; m < 2; m++) {
    #pragma unroll
    for (int r = 0; r < 4; r++) {
      float d = den[m][r];
      d += __shfl_xor(d, 1); d += __shfl_xor(d, 2);
      d += __shfl_xor(d, 4); d += __shfl_xor(d, 8);
      den[m][r] = 1.0f / d;
    }
  }
  #pragma unroll
  for (int m = 0; m < 2; m++) {
    const long row = b * 2048 + qrow0 + m * 16 + lg * 4;
    #pragma unroll
    for (int df = 0; df < 8; df++) {
      const int col = h * 128 + df * 16 + l15;
      #pragma unroll
      for (int r = 0; r < 4; r++)
        ctx[(row + r) * 2048 + col] = f2bf(o[m][df][r] * den[m][r]);
    }
  }
}

// ---------------- launch ----------------
extern "C" void kernel_launch(void* const* d_in, const int* in_sizes, int n_in,
                              void* d_out, int out_size, void* d_ws, size_t ws_size,
                              hipStream_t stream) {
  const float* x    = (const float*)d_in[0];
  const int*   mask = (const int*)d_in[1];
  const float* Wq   = (const float*)d_in[2];
  const float* bq   = (const float*)d_in[3];
  const float* Wk   = (const float*)d_in[4];
  const float* bk   = (const float*)d_in[5];
  const float* Wv   = (const float*)d_in[6];
  const float* bv   = (const float*)d_in[7];
  const float* Wo   = (const float*)d_in[8];
  const float* bo   = (const float*)d_in[9];
  const float* asc  = (const float*)d_in[10];
  float* out = (float*)d_out;

  unsigned short* w   = (unsigned short*)d_ws;
  unsigned short* Xb  = w;                 // 8388608 elems (also reused as Ctx later)
  unsigned short* Wqb = Xb  + XN;          // 4194304
  unsigned short* Wkb = Wqb + WN;
  unsigned short* Wvb = Wkb + WN;
  unsigned short* Wob = Wvb + WN;
  unsigned short* Qb  = Wob + WN;          // 8388608
  unsigned short* Kbf = Qb  + XN;
  unsigned short* Vb  = Kbf + XN;
  unsigned short* Vt  = Vb  + XN;
  unsigned short* Ctx = Xb;                // alias: X no longer needed after QKV GEMMs

  cast5_kernel<<<2048, 256, 0, stream>>>(x, Wq, Wk, Wv, Wo, Xb);

  dim3 g(16, 32);  // N/128, M/128
  gemm_bt<1><<<g, 256, 0, stream>>>(Xb, Wqb, bq, Qb,  4096, 2048, 2048);
  gemm_bt<1><<<g, 256, 0, stream>>>(Xb, Wkb, bk, Kbf, 4096, 2048, 2048);
  gemm_bt<1><<<g, 256, 0, stream>>>(Xb, Wvb, bv, Vb,  4096, 2048, 2048);

  norm_qk<<<32768, 256, 0, stream>>>(Qb, Kbf, asc);
  transpose_v<<<dim3(32, 2, 32), 256, 0, stream>>>(Vb, Vt);

  attn_kernel<<<dim3(16, 32), 256, 0, stream>>>(Qb, Kbf, Vt, mask, Ctx);

  gemm_bt<0><<<g, 256, 0, stream>>>(Ctx, Wob, bo, out, 4096, 2048, 2048);
}

// Round 3
// 488.735 us; speedup vs baseline: 1.3802x; 1.3802x over previous
//
#include <hip/hip_runtime.h>
#include <hip/hip_bf16.h>
#include <stdint.h>

// MultiHeadAttention_79714593013958 — cosine-normalized MHA, MI355X bf16 MFMA pipeline.
// bs=2, qlen=2048, dim=2048, heads=16, dph=128.
//
//  1) cast5:      X, Wq, Wk, Wv, Wo f32->bf16 ; mask -> additive bias (0 / -1e5)
//  2) gemm_bt x3: Q/K/V = X @ W^T + b (bf16)
//  3) norm_qk:    per-(row,head) L2 normalize Q (xscale) and K in place
//  4) transpose_v: V -> Vt[bh][d][s]
//  5) attn v3:    LDS-staged K/V tiles (source-side XOR swizzle, verified algebra),
//                 counted-vmcnt K/V pipeline, v1's known-correct P path
//                 (wave-private padded LDS round-trip)
//  6) gemm_bt:    out = ctx @ Wo^T + bo (f32)

typedef __attribute__((ext_vector_type(8))) short bf16x8;
typedef __attribute__((ext_vector_type(4))) float f32x4;
typedef __attribute__((ext_vector_type(8))) unsigned short u16x8;

#define XN 8388608L   // 2*2048*2048
#define WN 4194304L   // 2048*2048

__device__ __forceinline__ float bf2f(unsigned short u) {
  union { unsigned int i; float f; } v; v.i = ((unsigned int)u) << 16; return v.f;
}
__device__ __forceinline__ unsigned short f2bf(float f) {
  union { float f; unsigned int i; } u; u.f = f;
  unsigned int r = u.i + 0x7FFFu + ((u.i >> 16) & 1u);
  return (unsigned short)(r >> 16);
}

__device__ __forceinline__ void gload_lds16(const void* g, void* l) {
  __builtin_amdgcn_global_load_lds((__attribute__((address_space(1))) void*)g,
                                   (__attribute__((address_space(3))) void*)l,
                                   16, 0, 0);
}

// ---------------- 1) f32 -> bf16 cast of X + 4 weights, mask -> bias ----------------
__global__ __launch_bounds__(256) void cast5_kernel(
    const float* __restrict__ x,  const float* __restrict__ w0,
    const float* __restrict__ w1, const float* __restrict__ w2,
    const float* __restrict__ w3, unsigned short* __restrict__ dst,
    const int* __restrict__ mask, float* __restrict__ biasf)
{
  const long total8 = (XN + 4 * WN) >> 3;
  const long tid0 = (long)blockIdx.x * blockDim.x + threadIdx.x;
  const long stride = (long)gridDim.x * blockDim.x;
  for (long i = tid0; i < total8; i += stride) {
    long e = i << 3;
    const float* src; long off;
    if (e < XN) { src = x; off = e; }
    else {
      long r = e - XN;
      int wi = (int)(r >> 22);
      off = r & (WN - 1);
      src = (wi == 0) ? w0 : (wi == 1) ? w1 : (wi == 2) ? w2 : w3;
    }
    const float4* p = (const float4*)(src + off);
    float4 a = p[0], b = p[1];
    u16x8 o;
    o[0] = f2bf(a.x); o[1] = f2bf(a.y); o[2] = f2bf(a.z); o[3] = f2bf(a.w);
    o[4] = f2bf(b.x); o[5] = f2bf(b.y); o[6] = f2bf(b.z); o[7] = f2bf(b.w);
    *(u16x8*)(dst + e) = o;
  }
  for (long j = tid0; j < 4096; j += stride)
    biasf[j] = (mask[j] != 0) ? 0.f : -1.0e5f;
}

// ---------------- 2/6) C[M,N] = A[M,K] * B[N,K]^T + bias, m97-style ----------------
template<int OUT_BF16>
__global__ __launch_bounds__(256) void gemm_bt(
    const unsigned short* __restrict__ A, const unsigned short* __restrict__ B,
    const float* __restrict__ bias, void* __restrict__ Cout,
    int M, int N, int K)
{
  __shared__ unsigned short As[128 * 32];
  __shared__ unsigned short Bs[128 * 32];
  const int t    = threadIdx.x;
  const int lane = t & 63;
  const int w    = t >> 6;
  const int wr   = w >> 1, wc = w & 1;
  const int l15  = lane & 15;
  const int koff = (lane >> 4) * 8;
  const int lg4  = (lane >> 4) * 4;

  const long Kl = K;
  const unsigned short* Ag0 = A + (long)(blockIdx.y * 128 + (t >> 2)) * Kl + (t & 3) * 8;
  const unsigned short* Bg0 = B + (long)(blockIdx.x * 128 + (t >> 2)) * Kl + (t & 3) * 8;
  unsigned short* Asl = As + t * 8;
  unsigned short* Bsl = Bs + t * 8;

  f32x4 acc[4][4];
  const f32x4 zero = {0.f, 0.f, 0.f, 0.f};
  #pragma unroll
  for (int m = 0; m < 4; m++)
    #pragma unroll
    for (int n = 0; n < 4; n++) acc[m][n] = zero;

  const int nK = K >> 5;
  for (int kk = 0; kk < nK; kk++) {
    const long ko = (long)kk * 32;
    gload_lds16(Ag0 + ko,            Asl);
    gload_lds16(Ag0 + 64 * Kl + ko,  Asl + 2048);
    gload_lds16(Bg0 + ko,            Bsl);
    gload_lds16(Bg0 + 64 * Kl + ko,  Bsl + 2048);
    __syncthreads();
    bf16x8 af[4], bfr[4];
    #pragma unroll
    for (int m = 0; m < 4; m++)
      af[m] = *(const bf16x8*)&As[(wr * 64 + m * 16 + l15) * 32 + koff];
    #pragma unroll
    for (int n = 0; n < 4; n++)
      bfr[n] = *(const bf16x8*)&Bs[(wc * 64 + n * 16 + l15) * 32 + koff];
    #pragma unroll
    for (int m = 0; m < 4; m++)
      #pragma unroll
      for (int n = 0; n < 4; n++)
        acc[m][n] = __builtin_amdgcn_mfma_f32_16x16x32_bf16(af[m], bfr[n], acc[m][n], 0, 0, 0);
    __syncthreads();
  }

  #pragma unroll
  for (int m = 0; m < 4; m++) {
    const int row = blockIdx.y * 128 + wr * 64 + m * 16 + lg4;
    #pragma unroll
    for (int n = 0; n < 4; n++) {
      const int col = blockIdx.x * 128 + wc * 64 + n * 16 + l15;
      const float bv = bias[col];
      #pragma unroll
      for (int r = 0; r < 4; r++) {
        float v = acc[m][n][r] + bv;
        if (OUT_BF16) ((unsigned short*)Cout)[(long)(row + r) * N + col] = f2bf(v);
        else          ((float*)Cout)[(long)(row + r) * N + col] = v;
      }
    }
  }
}

// ---------------- 3) per-(row,head) L2 norm of Q (x scale) and K ----------------
__global__ __launch_bounds__(256) void norm_qk(unsigned short* __restrict__ Q,
                                               unsigned short* __restrict__ Kb,
                                               const float* __restrict__ scale_p)
{
  const int w = threadIdx.x >> 6, lane = threadIdx.x & 63;
  const long id = (long)blockIdx.x * 4 + w;
  const int isK = id >= 65536;
  const long p = isK ? id - 65536 : id;
  unsigned short* base = (isK ? Kb : Q) + (p >> 4) * 2048 + (p & 15) * 128 + lane * 2;
  unsigned int v = *(const unsigned int*)base;
  float x0 = bf2f((unsigned short)(v & 0xffffu));
  float x1 = bf2f((unsigned short)(v >> 16));
  float ss = x0 * x0 + x1 * x1;
  ss += __shfl_xor(ss, 1);  ss += __shfl_xor(ss, 2);  ss += __shfl_xor(ss, 4);
  ss += __shfl_xor(ss, 8);  ss += __shfl_xor(ss, 16); ss += __shfl_xor(ss, 32);
  float inv = rsqrtf(fmaxf(ss, 1e-24f));
  if (!isK) inv *= *scale_p;
  unsigned int o = (unsigned int)f2bf(x0 * inv) | ((unsigned int)f2bf(x1 * inv) << 16);
  *(unsigned int*)base = o;
}

// ---------------- 4) V[b*2048+s][h*128+d] -> Vt[bh][d][s] ----------------
__global__ __launch_bounds__(256) void transpose_v(const unsigned short* __restrict__ V,
                                                   unsigned short* __restrict__ Vt)
{
  __shared__ unsigned short tile[64][66];
  const int bh = blockIdx.z;
  const int b = bh >> 4, h = bh & 15;
  const int s0 = blockIdx.x * 64;
  const int d0 = blockIdx.y * 64;
  const int t = threadIdx.x;
  const int c = t & 63, r4 = t >> 6;
  #pragma unroll
  for (int i = 0; i < 16; i++) {
    int r = r4 + i * 4;
    tile[r][c] = V[(long)(b * 2048 + s0 + r) * 2048 + h * 128 + d0 + c];
  }
  __syncthreads();
  #pragma unroll
  for (int i = 0; i < 16; i++) {
    int dd = r4 + i * 4;
    Vt[((long)bh * 128 + d0 + dd) * 2048 + s0 + c] = tile[c][dd];
  }
}

// ---------------- 5) fused cosine attention v3 ----------------
// grid (16 q-tiles, 32 bh), 4 waves/block, wave owns 32 q-rows.
// K tile [64 k][256B] and V tile [128 d][128B] staged in LDS via global_load_lds
// with source-side XOR swizzle byte ^= ((row&7)<<4); reads un-swizzle with the
// same XOR. Counted-vmcnt pipeline: K leads by one tile; raw s_barrier only.
// P round-trip via wave-private padded LDS (known-correct v1 path).
__global__ __launch_bounds__(256, 2) void attn_kernel(
    const unsigned short* __restrict__ Q,
    const unsigned short* __restrict__ Kg_,
    const unsigned short* __restrict__ Vt_,
    const float* __restrict__ biasArr,   // [2][2048]: 0 or -1e5
    unsigned short* __restrict__ ctx)
{
  __shared__ unsigned char KS[16384];
  __shared__ unsigned char VS[16384];
  __shared__ unsigned short Pl[4][32][72];

  const int bh = blockIdx.y, b = bh >> 4, h = bh & 15;
  const int t = threadIdx.x, w = t >> 6, lane = t & 63;
  const int l15 = lane & 15, lg = lane >> 4;
  const int xork = (l15 & 7) << 4;
  const int qrow0 = blockIdx.x * 128 + w * 32;

  // Q fragments (A operand): rows qrow0+m*16+l15, k = dk*32 + lg*8 + 0..7
  bf16x8 aq[2][4];
  #pragma unroll
  for (int m = 0; m < 2; m++)
    #pragma unroll
    for (int dk = 0; dk < 4; dk++)
      aq[m][dk] = *(const bf16x8*)&Q[(long)(b * 2048 + qrow0 + m * 16 + l15) * 2048
                                     + h * 128 + dk * 32 + lg * 8];

  // staging: 1024 x 16B chunks per tile, 4 per thread, src pre-swizzled, dst linear
  const char* Kgp = (const char*)(Kg_ + (long)b * 2048 * 2048 + h * 128);
  const char* Vgp = (const char*)(Vt_ + (long)bh * 128 * 2048);
  const int rK = t >> 4;              // K row 0..15 (+16 per i)
  const int rV = t >> 3;              // V row 0..31 (+32 per i)
  const char* srcK0 = Kgp + (long)rK * 4096 + (((t & 15) * 16) ^ ((rK & 7) << 4));
  const char* srcV0 = Vgp + (long)rV * 4096 + (((t & 7) * 16) ^ ((rV & 7) << 4));
  char* dstK0 = (char*)KS + t * 16;
  char* dstV0 = (char*)VS + t * 16;

  f32x4 o[2][8]; float den[2][4];
  const f32x4 zero = {0.f, 0.f, 0.f, 0.f};
  #pragma unroll
  for (int m = 0; m < 2; m++) {
    #pragma unroll
    for (int df = 0; df < 8; df++) o[m][df] = zero;
    #pragma unroll
    for (int r = 0; r < 4; r++) den[m][r] = 0.f;
  }

  const char* KSc = (const char*)KS;
  const char* VSc = (const char*)VS;
  int cK[4], cV2[2];
  #pragma unroll
  for (int dk = 0; dk < 4; dk++) cK[dk] = (dk * 64 + lg * 16) ^ xork;
  #pragma unroll
  for (int kk = 0; kk < 2; kk++) cV2[kk] = (kk * 64 + lg * 16) ^ xork;
  const int rowK = l15 * 256, rowV = l15 * 128;

  // prologue: issue K(0) then V(0)
  #pragma unroll
  for (int i = 0; i < 4; i++) gload_lds16(srcK0 + i * 65536,  dstK0 + i * 4096);
  #pragma unroll
  for (int i = 0; i < 4; i++) gload_lds16(srcV0 + i * 131072, dstV0 + i * 4096);

  const float* brow = biasArr + b * 2048 + l15;
  const float L2E = 1.44269504088896f;

  for (int kt = 0; kt < 32; kt++) {
    const int k0 = kt * 64;
    // ---- top: K(kt) landed (V(kt)'s 4 loads may remain in flight) ----
    asm volatile("s_waitcnt vmcnt(4)" ::: "memory");
    __builtin_amdgcn_s_barrier();
    __builtin_amdgcn_sched_barrier(0);

    float bn[4];
    #pragma unroll
    for (int n = 0; n < 4; n++) bn[n] = brow[k0 + n * 16];

    // ---- QK^T from KS ----
    f32x4 s[2][4];
    #pragma unroll
    for (int m = 0; m < 2; m++)
      #pragma unroll
      for (int n = 0; n < 4; n++) s[m][n] = zero;
    __builtin_amdgcn_s_setprio(1);
    #pragma unroll
    for (int n = 0; n < 4; n++) {
      #pragma unroll
      for (int dk = 0; dk < 4; dk++) {
        bf16x8 bk = *(const bf16x8*)(KSc + n * 4096 + rowK + cK[dk]);
        s[0][n] = __builtin_amdgcn_mfma_f32_16x16x32_bf16(aq[0][dk], bk, s[0][n], 0, 0, 0);
        s[1][n] = __builtin_amdgcn_mfma_f32_16x16x32_bf16(aq[1][dk], bk, s[1][n], 0, 0, 0);
      }
    }
    __builtin_amdgcn_s_setprio(0);

    // ---- softmax (|s| <= scale => no max) + P to wave-private LDS ----
    #pragma unroll
    for (int n = 0; n < 4; n++) {
      #pragma unroll
      for (int m = 0; m < 2; m++) {
        #pragma unroll
        for (int r = 0; r < 4; r++) {
          float e = exp2f(fmaf(s[m][n][r], L2E, bn[n]));
          den[m][r] += e;
          Pl[w][m * 16 + lg * 4 + r][n * 16 + l15] = f2bf(e);
        }
      }
    }

    // ---- V(kt) landed; all waves done with KS -> prefetch K(kt+1) ----
    asm volatile("s_waitcnt vmcnt(0)" ::: "memory");
    __builtin_amdgcn_s_barrier();
    __builtin_amdgcn_sched_barrier(0);
    if (kt < 31) {
      const long kof = (long)(kt + 1) * 262144;
      #pragma unroll
      for (int i = 0; i < 4; i++) gload_lds16(srcK0 + kof + i * 65536, dstK0 + i * 4096);
    }

    // ---- PV: A-frag from Pl (compiler-tracked dep), B-frag from VS ----
    #pragma unroll
    for (int kk = 0; kk < 2; kk++) {
      bf16x8 ap0 = *(const bf16x8*)&Pl[w][l15][kk * 32 + lg * 8];
      bf16x8 ap1 = *(const bf16x8*)&Pl[w][16 + l15][kk * 32 + lg * 8];
      bf16x8 bv[8];
      #pragma unroll
      for (int df = 0; df < 8; df++)
        bv[df] = *(const bf16x8*)(VSc + df * 2048 + rowV + cV2[kk]);
      __builtin_amdgcn_s_setprio(1);
      #pragma unroll
      for (int df = 0; df < 8; df++) {
        o[0][df] = __builtin_amdgcn_mfma_f32_16x16x32_bf16(ap0, bv[df], o[0][df], 0, 0, 0);
        o[1][df] = __builtin_amdgcn_mfma_f32_16x16x32_bf16(ap1, bv[df], o[1][df], 0, 0, 0);
      }
      __builtin_amdgcn_s_setprio(0);
    }

    // ---- all waves done with VS -> prefetch V(kt+1) ----
    __builtin_amdgcn_s_barrier();
    __builtin_amdgcn_sched_barrier(0);
    if (kt < 31) {
      const long vof = (long)(kt + 1) * 128;
      #pragma unroll
      for (int i = 0; i < 4; i++) gload_lds16(srcV0 + vof + i * 131072, dstV0 + i * 4096);
    }
  }

  // ---- den reduce over key-lane groups, then ctx = O/den ----
  #pragma unroll
  for (int m = 0; m < 2; m++)
    #pragma unroll
    for (int r = 0; r < 4; r++) {
      float d = den[m][r];
      d += __shfl_xor(d, 1); d += __shfl_xor(d, 2);
      d += __shfl_xor(d, 4); d += __shfl_xor(d, 8);
      den[m][r] = 1.0f / d;
    }
  #pragma unroll
  for (int m = 0; m < 2; m++) {
    const long row = b * 2048 + qrow0 + m * 16 + lg * 4;
    #pragma unroll
    for (int df = 0; df < 8; df++) {
      const int col = h * 128 + df * 16 + l15;
      #pragma unroll
      for (int r = 0; r < 4; r++)
        ctx[(row + r) * 2048 + col] = f2bf(o[m][df][r] * den[m][r]);
    }
  }
}

// ---------------- launch ----------------
extern "C" void kernel_launch(void* const* d_in, const int* in_sizes, int n_in,
                              void* d_out, int out_size, void* d_ws, size_t ws_size,
                              hipStream_t stream) {
  const float* x    = (const float*)d_in[0];
  const int*   mask = (const int*)d_in[1];
  const float* Wq   = (const float*)d_in[2];
  const float* bq   = (const float*)d_in[3];
  const float* Wk   = (const float*)d_in[4];
  const float* bk   = (const float*)d_in[5];
  const float* Wv   = (const float*)d_in[6];
  const float* bv   = (const float*)d_in[7];
  const float* Wo   = (const float*)d_in[8];
  const float* bo   = (const float*)d_in[9];
  const float* asc  = (const float*)d_in[10];
  float* out = (float*)d_out;

  unsigned short* w   = (unsigned short*)d_ws;
  unsigned short* Xb  = w;
  unsigned short* Wqb = Xb  + XN;
  unsigned short* Wkb = Wqb + WN;
  unsigned short* Wvb = Wkb + WN;
  unsigned short* Wob = Wvb + WN;
  unsigned short* Qb  = Wob + WN;
  unsigned short* Kbf = Qb  + XN;
  unsigned short* Vb  = Kbf + XN;
  unsigned short* Vt  = Vb  + XN;
  float*          Bias = (float*)(Vt + XN);
  unsigned short* Ctx = Xb;   // alias: X dead after QKV GEMMs

  cast5_kernel<<<2048, 256, 0, stream>>>(x, Wq, Wk, Wv, Wo, Xb, mask, Bias);

  dim3 g(16, 32);
  gemm_bt<1><<<g, 256, 0, stream>>>(Xb, Wqb, bq, Qb,  4096, 2048, 2048);
  gemm_bt<1><<<g, 256, 0, stream>>>(Xb, Wkb, bk, Kbf, 4096, 2048, 2048);
  gemm_bt<1><<<g, 256, 0, stream>>>(Xb, Wvb, bv, Vb,  4096, 2048, 2048);

  norm_qk<<<32768, 256, 0, stream>>>(Qb, Kbf, asc);
  transpose_v<<<dim3(32, 2, 32), 256, 0, stream>>>(Vb, Vt);

  attn_kernel<<<dim3(16, 32), 256, 0, stream>>>(Qb, Kbf, Vt, Bias, Ctx);

  gemm_bt<0><<<g, 256, 0, stream>>>(Ctx, Wob, bo, out, 4096, 2048, 2048);
}

// Round 4
// 459.452 us; speedup vs baseline: 1.4682x; 1.0637x over previous
//
#include <hip/hip_runtime.h>
#include <hip/hip_bf16.h>
#include <stdint.h>

// MultiHeadAttention_79714593013958 — cosine-normalized MHA, MI355X bf16 MFMA pipeline.
// bs=2, qlen=2048, dim=2048, heads=16, dph=128.
//
//  1) cast5:     X, Wq, Wk, Wv, Wo f32->bf16 ; mask -> additive bias (0 / -1e5)
//  2) gemm2<0>:  Q,K = X @ {Wq,Wk}^T + b (merged, 1024 blocks, dbuf pipeline)
//  3) gemm2<1>:  Vt = Wv @ X^T (+bv per-row) written directly as [bh][d][s]
//  4) norm_qk:   per-(row,head) L2 normalize Q (xscale) and K in place
//  5) attn:      LDS-staged K/V tiles, counted-vmcnt pipeline (v3, unchanged)
//  6) gemm2<2>:  out = ctx @ Wo^T + bo (f32)

typedef __attribute__((ext_vector_type(8))) short bf16x8;
typedef __attribute__((ext_vector_type(4))) float f32x4;
typedef __attribute__((ext_vector_type(8))) unsigned short u16x8;

#define XN 8388608L   // 2*2048*2048
#define WN 4194304L   // 2048*2048

__device__ __forceinline__ float bf2f(unsigned short u) {
  union { unsigned int i; float f; } v; v.i = ((unsigned int)u) << 16; return v.f;
}
__device__ __forceinline__ unsigned short f2bf(float f) {
  union { float f; unsigned int i; } u; u.f = f;
  unsigned int r = u.i + 0x7FFFu + ((u.i >> 16) & 1u);
  return (unsigned short)(r >> 16);
}

__device__ __forceinline__ void gload_lds16(const void* g, void* l) {
  __builtin_amdgcn_global_load_lds((__attribute__((address_space(1))) void*)g,
                                   (__attribute__((address_space(3))) void*)l,
                                   16, 0, 0);
}

// ---------------- 1) f32 -> bf16 cast of X + 4 weights, mask -> bias ----------------
__global__ __launch_bounds__(256) void cast5_kernel(
    const float* __restrict__ x,  const float* __restrict__ w0,
    const float* __restrict__ w1, const float* __restrict__ w2,
    const float* __restrict__ w3, unsigned short* __restrict__ dst,
    const int* __restrict__ mask, float* __restrict__ biasf)
{
  const long total8 = (XN + 4 * WN) >> 3;
  const long tid0 = (long)blockIdx.x * blockDim.x + threadIdx.x;
  const long stride = (long)gridDim.x * blockDim.x;
  for (long i = tid0; i < total8; i += stride) {
    long e = i << 3;
    const float* src; long off;
    if (e < XN) { src = x; off = e; }
    else {
      long r = e - XN;
      int wi = (int)(r >> 22);
      off = r & (WN - 1);
      src = (wi == 0) ? w0 : (wi == 1) ? w1 : (wi == 2) ? w2 : w3;
    }
    const float4* p = (const float4*)(src + off);
    float4 a = p[0], b = p[1];
    u16x8 o;
    o[0] = f2bf(a.x); o[1] = f2bf(a.y); o[2] = f2bf(a.z); o[3] = f2bf(a.w);
    o[4] = f2bf(b.x); o[5] = f2bf(b.y); o[6] = f2bf(b.z); o[7] = f2bf(b.w);
    *(u16x8*)(dst + e) = o;
  }
  for (long j = tid0; j < 4096; j += stride)
    biasf[j] = (mask[j] != 0) ? 0.f : -1.0e5f;
}

// ---------------- 2/3/6) double-buffered 128x128 BT-GEMM, K=2048 ----------------
// MODE 0: merged Q,K.  A=X[4096][2048], B=Wq|Wk (contiguous), bias bq/bk per-col,
//         C bf16 Q|K (contiguous, row*2048+col). 1024 blocks.
// MODE 1: Vt. A=Wv[2048][2048], B=X[4096][2048], bias bv per-ROW,
//         C bf16 at row*2048 + (col&2047) + (col>>11)*4194304  (= Vt[bh][d][s]). 512 blocks.
// MODE 2: out. A=Ctx[4096][2048], B=Wo, bias bo per-col, C f32 row*2048+col. 512 blocks.
template<int MODE>
__global__ __launch_bounds__(256) void gemm2(
    const unsigned short* __restrict__ A, const unsigned short* __restrict__ Bmat,
    const float* __restrict__ bias0, const float* __restrict__ bias1,
    void* __restrict__ Cout)
{
  constexpr int NWG = (MODE == 0) ? 1024 : 512;
  __shared__ unsigned short As[2][4096];
  __shared__ unsigned short Bs[2][4096];

  // XCD-aware bijective swizzle (NWG % 8 == 0)
  const int bid = blockIdx.x;
  const int id = (bid & 7) * (NWG / 8) + (bid >> 3);

  int mat, bx, by;
  if (MODE == 0)      { mat = id >> 9; int rem = id & 511; bx = rem & 15; by = rem >> 4; }
  else if (MODE == 1) { mat = 0; bx = id & 31; by = id >> 5; }
  else                { mat = 0; bx = id & 15; by = id >> 4; }

  const unsigned short* Bb = (MODE == 0) ? (Bmat + (long)mat * WN) : Bmat;
  const float* bias = (MODE == 0) ? (mat ? bias1 : bias0) : bias0;

  const int t    = threadIdx.x;
  const int lane = t & 63;
  const int w    = t >> 6;
  const int wr   = w >> 1, wc = w & 1;
  const int l15  = lane & 15;
  const int koff = (lane >> 4) * 8;
  const int lg4  = (lane >> 4) * 4;

  const unsigned short* Ag0 = A  + (long)(by * 128 + (t >> 2)) * 2048 + (t & 3) * 8;
  const unsigned short* Bg0 = Bb + (long)(bx * 128 + (t >> 2)) * 2048 + (t & 3) * 8;

  f32x4 acc[4][4];
  const f32x4 zero = {0.f, 0.f, 0.f, 0.f};
  #pragma unroll
  for (int m = 0; m < 4; m++)
    #pragma unroll
    for (int n = 0; n < 4; n++) acc[m][n] = zero;

  auto stage = [&](int buf, int kk) {
    const long ko = (long)kk * 32;
    gload_lds16(Ag0 + ko,              &As[buf][t * 8]);
    gload_lds16(Ag0 + 64 * 2048 + ko,  &As[buf][t * 8 + 2048]);
    gload_lds16(Bg0 + ko,              &Bs[buf][t * 8]);
    gload_lds16(Bg0 + 64 * 2048 + ko,  &Bs[buf][t * 8 + 2048]);
  };

  auto body = [&](int bufR, int kk, int bufW) {
    if (kk + 1 < 64) stage(bufW, kk + 1);   // prefetch next tile (hidden under compute)
    bf16x8 af[4], bfr[4];
    #pragma unroll
    for (int m = 0; m < 4; m++)
      af[m] = *(const bf16x8*)&As[bufR][(wr * 64 + m * 16 + l15) * 32 + koff];
    #pragma unroll
    for (int n = 0; n < 4; n++)
      bfr[n] = *(const bf16x8*)&Bs[bufR][(wc * 64 + n * 16 + l15) * 32 + koff];
    __builtin_amdgcn_s_setprio(1);
    #pragma unroll
    for (int m = 0; m < 4; m++)
      #pragma unroll
      for (int n = 0; n < 4; n++)
        acc[m][n] = __builtin_amdgcn_mfma_f32_16x16x32_bf16(af[m], bfr[n], acc[m][n], 0, 0, 0);
    __builtin_amdgcn_s_setprio(0);
    asm volatile("s_waitcnt vmcnt(0)" ::: "memory");  // prefetch landed
    __builtin_amdgcn_s_barrier();                      // all waves done reading bufR
    __builtin_amdgcn_sched_barrier(0);
  };

  // prologue: tile 0 into buf0
  stage(0, 0);
  asm volatile("s_waitcnt vmcnt(0)" ::: "memory");
  __builtin_amdgcn_s_barrier();
  __builtin_amdgcn_sched_barrier(0);

  for (int kk = 0; kk < 64; kk += 2) {
    body(0, kk,     1);
    body(1, kk + 1, 0);
  }

  #pragma unroll
  for (int m = 0; m < 4; m++) {
    const int row = by * 128 + wr * 64 + m * 16 + lg4;
    #pragma unroll
    for (int n = 0; n < 4; n++) {
      const int col = bx * 128 + wc * 64 + n * 16 + l15;
      #pragma unroll
      for (int r = 0; r < 4; r++) {
        float v = acc[m][n][r];
        if (MODE == 0) {
          v += bias[col];
          ((unsigned short*)Cout + (long)mat * XN)[(long)(row + r) * 2048 + col] = f2bf(v);
        } else if (MODE == 1) {
          v += bias[row + r];
          ((unsigned short*)Cout)[(long)(row + r) * 2048 + (col & 2047)
                                  + (long)(col >> 11) * 4194304] = f2bf(v);
        } else {
          v += bias[col];
          ((float*)Cout)[(long)(row + r) * 2048 + col] = v;
        }
      }
    }
  }
}

// ---------------- 4) per-(row,head) L2 norm of Q (x scale) and K ----------------
__global__ __launch_bounds__(256) void norm_qk(unsigned short* __restrict__ Q,
                                               unsigned short* __restrict__ Kb,
                                               const float* __restrict__ scale_p)
{
  const int w = threadIdx.x >> 6, lane = threadIdx.x & 63;
  const long id = (long)blockIdx.x * 4 + w;
  const int isK = id >= 65536;
  const long p = isK ? id - 65536 : id;
  unsigned short* base = (isK ? Kb : Q) + (p >> 4) * 2048 + (p & 15) * 128 + lane * 2;
  unsigned int v = *(const unsigned int*)base;
  float x0 = bf2f((unsigned short)(v & 0xffffu));
  float x1 = bf2f((unsigned short)(v >> 16));
  float ss = x0 * x0 + x1 * x1;
  ss += __shfl_xor(ss, 1);  ss += __shfl_xor(ss, 2);  ss += __shfl_xor(ss, 4);
  ss += __shfl_xor(ss, 8);  ss += __shfl_xor(ss, 16); ss += __shfl_xor(ss, 32);
  float inv = rsqrtf(fmaxf(ss, 1e-24f));
  if (!isK) inv *= *scale_p;
  unsigned int o = (unsigned int)f2bf(x0 * inv) | ((unsigned int)f2bf(x1 * inv) << 16);
  *(unsigned int*)base = o;
}

// ---------------- 5) fused cosine attention (v3, unchanged) ----------------
__global__ __launch_bounds__(256, 2) void attn_kernel(
    const unsigned short* __restrict__ Q,
    const unsigned short* __restrict__ Kg_,
    const unsigned short* __restrict__ Vt_,
    const float* __restrict__ biasArr,
    unsigned short* __restrict__ ctx)
{
  __shared__ unsigned char KS[16384];
  __shared__ unsigned char VS[16384];
  __shared__ unsigned short Pl[4][32][72];

  const int bh = blockIdx.y, b = bh >> 4, h = bh & 15;
  const int t = threadIdx.x, w = t >> 6, lane = t & 63;
  const int l15 = lane & 15, lg = lane >> 4;
  const int xork = (l15 & 7) << 4;
  const int qrow0 = blockIdx.x * 128 + w * 32;

  bf16x8 aq[2][4];
  #pragma unroll
  for (int m = 0; m < 2; m++)
    #pragma unroll
    for (int dk = 0; dk < 4; dk++)
      aq[m][dk] = *(const bf16x8*)&Q[(long)(b * 2048 + qrow0 + m * 16 + l15) * 2048
                                     + h * 128 + dk * 32 + lg * 8];

  const char* Kgp = (const char*)(Kg_ + (long)b * 2048 * 2048 + h * 128);
  const char* Vgp = (const char*)(Vt_ + (long)bh * 128 * 2048);
  const int rK = t >> 4;
  const int rV = t >> 3;
  const char* srcK0 = Kgp + (long)rK * 4096 + (((t & 15) * 16) ^ ((rK & 7) << 4));
  const char* srcV0 = Vgp + (long)rV * 4096 + (((t & 7) * 16) ^ ((rV & 7) << 4));
  char* dstK0 = (char*)KS + t * 16;
  char* dstV0 = (char*)VS + t * 16;

  f32x4 o[2][8]; float den[2][4];
  const f32x4 zero = {0.f, 0.f, 0.f, 0.f};
  #pragma unroll
  for (int m = 0; m < 2; m++) {
    #pragma unroll
    for (int df = 0; df < 8; df++) o[m][df] = zero;
    #pragma unroll
    for (int r = 0; r < 4; r++) den[m][r] = 0.f;
  }

  const char* KSc = (const char*)KS;
  const char* VSc = (const char*)VS;
  int cK[4], cV2[2];
  #pragma unroll
  for (int dk = 0; dk < 4; dk++) cK[dk] = (dk * 64 + lg * 16) ^ xork;
  #pragma unroll
  for (int kk = 0; kk < 2; kk++) cV2[kk] = (kk * 64 + lg * 16) ^ xork;
  const int rowK = l15 * 256, rowV = l15 * 128;

  #pragma unroll
  for (int i = 0; i < 4; i++) gload_lds16(srcK0 + i * 65536,  dstK0 + i * 4096);
  #pragma unroll
  for (int i = 0; i < 4; i++) gload_lds16(srcV0 + i * 131072, dstV0 + i * 4096);

  const float* brow = biasArr + b * 2048 + l15;
  const float L2E = 1.44269504088896f;

  for (int kt = 0; kt < 32; kt++) {
    const int k0 = kt * 64;
    asm volatile("s_waitcnt vmcnt(4)" ::: "memory");
    __builtin_amdgcn_s_barrier();
    __builtin_amdgcn_sched_barrier(0);

    float bn[4];
    #pragma unroll
    for (int n = 0; n < 4; n++) bn[n] = brow[k0 + n * 16];

    f32x4 s[2][4];
    #pragma unroll
    for (int m = 0; m < 2; m++)
      #pragma unroll
      for (int n = 0; n < 4; n++) s[m][n] = zero;
    __builtin_amdgcn_s_setprio(1);
    #pragma unroll
    for (int n = 0; n < 4; n++) {
      #pragma unroll
      for (int dk = 0; dk < 4; dk++) {
        bf16x8 bk = *(const bf16x8*)(KSc + n * 4096 + rowK + cK[dk]);
        s[0][n] = __builtin_amdgcn_mfma_f32_16x16x32_bf16(aq[0][dk], bk, s[0][n], 0, 0, 0);
        s[1][n] = __builtin_amdgcn_mfma_f32_16x16x32_bf16(aq[1][dk], bk, s[1][n], 0, 0, 0);
      }
    }
    __builtin_amdgcn_s_setprio(0);

    #pragma unroll
    for (int n = 0; n < 4; n++) {
      #pragma unroll
      for (int m = 0; m < 2; m++) {
        #pragma unroll
        for (int r = 0; r < 4; r++) {
          float e = exp2f(fmaf(s[m][n][r], L2E, bn[n]));
          den[m][r] += e;
          Pl[w][m * 16 + lg * 4 + r][n * 16 + l15] = f2bf(e);
        }
      }
    }

    asm volatile("s_waitcnt vmcnt(0)" ::: "memory");
    __builtin_amdgcn_s_barrier();
    __builtin_amdgcn_sched_barrier(0);
    if (kt < 31) {
      const long kof = (long)(kt + 1) * 262144;
      #pragma unroll
      for (int i = 0; i < 4; i++) gload_lds16(srcK0 + kof + i * 65536, dstK0 + i * 4096);
    }

    #pragma unroll
    for (int kk = 0; kk < 2; kk++) {
      bf16x8 ap0 = *(const bf16x8*)&Pl[w][l15][kk * 32 + lg * 8];
      bf16x8 ap1 = *(const bf16x8*)&Pl[w][16 + l15][kk * 32 + lg * 8];
      bf16x8 bv[8];
      #pragma unroll
      for (int df = 0; df < 8; df++)
        bv[df] = *(const bf16x8*)(VSc + df * 2048 + rowV + cV2[kk]);
      __builtin_amdgcn_s_setprio(1);
      #pragma unroll
      for (int df = 0; df < 8; df++) {
        o[0][df] = __builtin_amdgcn_mfma_f32_16x16x32_bf16(ap0, bv[df], o[0][df], 0, 0, 0);
        o[1][df] = __builtin_amdgcn_mfma_f32_16x16x32_bf16(ap1, bv[df], o[1][df], 0, 0, 0);
      }
      __builtin_amdgcn_s_setprio(0);
    }

    __builtin_amdgcn_s_barrier();
    __builtin_amdgcn_sched_barrier(0);
    if (kt < 31) {
      const long vof = (long)(kt + 1) * 128;
      #pragma unroll
      for (int i = 0; i < 4; i++) gload_lds16(srcV0 + vof + i * 131072, dstV0 + i * 4096);
    }
  }

  #pragma unroll
  for (int m = 0; m < 2; m++)
    #pragma unroll
    for (int r = 0; r < 4; r++) {
      float d = den[m][r];
      d += __shfl_xor(d, 1); d += __shfl_xor(d, 2);
      d += __shfl_xor(d, 4); d += __shfl_xor(d, 8);
      den[m][r] = 1.0f / d;
    }
  #pragma unroll
  for (int m = 0; m < 2; m++) {
    const long row = b * 2048 + qrow0 + m * 16 + lg * 4;
    #pragma unroll
    for (int df = 0; df < 8; df++) {
      const int col = h * 128 + df * 16 + l15;
      #pragma unroll
      for (int r = 0; r < 4; r++)
        ctx[(row + r) * 2048 + col] = f2bf(o[m][df][r] * den[m][r]);
    }
  }
}

// ---------------- launch ----------------
extern "C" void kernel_launch(void* const* d_in, const int* in_sizes, int n_in,
                              void* d_out, int out_size, void* d_ws, size_t ws_size,
                              hipStream_t stream) {
  const float* x    = (const float*)d_in[0];
  const int*   mask = (const int*)d_in[1];
  const float* Wq   = (const float*)d_in[2];
  const float* bq   = (const float*)d_in[3];
  const float* Wk   = (const float*)d_in[4];
  const float* bk   = (const float*)d_in[5];
  const float* Wv   = (const float*)d_in[6];
  const float* bv   = (const float*)d_in[7];
  const float* Wo   = (const float*)d_in[8];
  const float* bo   = (const float*)d_in[9];
  const float* asc  = (const float*)d_in[10];
  float* out = (float*)d_out;

  unsigned short* w   = (unsigned short*)d_ws;
  unsigned short* Xb  = w;
  unsigned short* Wqb = Xb  + XN;   // Wkb = Wqb + WN (contiguous, used by gemm2<0>)
  unsigned short* Wvb = Wqb + 2 * WN;
  unsigned short* Wob = Wvb + WN;
  unsigned short* Qb  = Wob + WN;
  unsigned short* Kbf = Qb  + XN;
  unsigned short* Vt  = Kbf + XN;
  float*          Bias = (float*)(Vt + XN);
  unsigned short* Ctx = Xb;   // alias: X dead after Q/K/Vt GEMMs

  cast5_kernel<<<2048, 256, 0, stream>>>(x, Wq, Wk, Wv, Wo, Xb, mask, Bias);

  gemm2<0><<<1024, 256, 0, stream>>>(Xb, Wqb, bq, bk, Qb);     // Q and K
  gemm2<1><<<512,  256, 0, stream>>>(Wvb, Xb, bv, bv, Vt);     // Vt = (X Wv^T)^T

  norm_qk<<<32768, 256, 0, stream>>>(Qb, Kbf, asc);

  attn_kernel<<<dim3(16, 32), 256, 0, stream>>>(Qb, Kbf, Vt, Bias, Ctx);

  gemm2<2><<<512, 256, 0, stream>>>(Ctx, Wob, bo, bo, out);
}

// Round 5
// 450.356 us; speedup vs baseline: 1.4979x; 1.0202x over previous
//
#include <hip/hip_runtime.h>
#include <hip/hip_bf16.h>
#include <stdint.h>

// MultiHeadAttention_79714593013958 — cosine-normalized MHA, MI355X bf16 MFMA pipeline.
// bs=2, qlen=2048, dim=2048, heads=16, dph=128.
//
//  1) cast5:     X, Wq, Wk, Wv, Wo f32->bf16 ; mask -> additive bias (0 / -1e5)
//  2) gemm8<0>:  Q,K = X @ {Wq,Wk}^T + b   (256 wgs, 256x256 tile, counted-vmcnt phases)
//  3) gemm8<1>:  Vt = Wv @ X^T (+bv per-row) written as [bh][d][s]  (128 wgs)
//  4) norm_qk:   per-(row,head) L2 normalize Q (xscale) and K in place
//  5) attn:      LDS-staged K/V tiles, counted-vmcnt pipeline (v3, unchanged)
//  6) gemm8<2>:  out = ctx @ Wo^T + bo (f32, 128 wgs)

typedef __attribute__((ext_vector_type(8))) short bf16x8;
typedef __attribute__((ext_vector_type(4))) float f32x4;
typedef __attribute__((ext_vector_type(8))) unsigned short u16x8;

#define XN 8388608L   // 2*2048*2048
#define WN 4194304L   // 2048*2048

__device__ __forceinline__ float bf2f(unsigned short u) {
  union { unsigned int i; float f; } v; v.i = ((unsigned int)u) << 16; return v.f;
}
__device__ __forceinline__ unsigned short f2bf(float f) {
  union { float f; unsigned int i; } u; u.f = f;
  unsigned int r = u.i + 0x7FFFu + ((u.i >> 16) & 1u);
  return (unsigned short)(r >> 16);
}

__device__ __forceinline__ void gload_lds16(const void* g, void* l) {
  __builtin_amdgcn_global_load_lds((__attribute__((address_space(1))) void*)g,
                                   (__attribute__((address_space(3))) void*)l,
                                   16, 0, 0);
}

// ---------------- 1) f32 -> bf16 cast of X + 4 weights, mask -> bias ----------------
__global__ __launch_bounds__(256) void cast5_kernel(
    const float* __restrict__ x,  const float* __restrict__ w0,
    const float* __restrict__ w1, const float* __restrict__ w2,
    const float* __restrict__ w3, unsigned short* __restrict__ dst,
    const int* __restrict__ mask, float* __restrict__ biasf)
{
  const long total8 = (XN + 4 * WN) >> 3;
  const long tid0 = (long)blockIdx.x * blockDim.x + threadIdx.x;
  const long stride = (long)gridDim.x * blockDim.x;
  for (long i = tid0; i < total8; i += stride) {
    long e = i << 3;
    const float* src; long off;
    if (e < XN) { src = x; off = e; }
    else {
      long r = e - XN;
      int wi = (int)(r >> 22);
      off = r & (WN - 1);
      src = (wi == 0) ? w0 : (wi == 1) ? w1 : (wi == 2) ? w2 : w3;
    }
    const float4* p = (const float4*)(src + off);
    float4 a = p[0], b = p[1];
    u16x8 o;
    o[0] = f2bf(a.x); o[1] = f2bf(a.y); o[2] = f2bf(a.z); o[3] = f2bf(a.w);
    o[4] = f2bf(b.x); o[5] = f2bf(b.y); o[6] = f2bf(b.z); o[7] = f2bf(b.w);
    *(u16x8*)(dst + e) = o;
  }
  for (long j = tid0; j < 4096; j += stride)
    biasf[j] = (mask[j] != 0) ? 0.f : -1.0e5f;
}

// ---------------- 2/3/6) 256x256-tile counted-vmcnt BT-GEMM, K=2048 ----------------
// 8 waves (2M x 4N), per-wave 128x64 output (acc[8][4]).
// LDS: 2 buf x { A[256 rows][32 k] , B[256 rows][32 k] } bf16 = 2 x 32 KB = 128 KB.
// Per K-tile (BK=64 = two K=32 halves), 4 phases:
//   P1: stage h1(t+1); read A[mh0,k0](4) + B[k0](4); 16 MFMA; barrier
//   P2: read A[mh1,k0](4); 16 MFMA; vmcnt(4) [h2(t) landed]; barrier
//   P3: stage h2(t+1); read A[mh0,k1](4) + B[k1](4); 16 MFMA; barrier
//   P4: read A[mh1,k1](4); 16 MFMA; vmcnt(4) [h1(t+1) landed]; barrier
// In-flight ledger (4 loads per stage): 8 -> 4 -> 8 -> 4; never drains to 0.
// Swizzle: 16B-chunk ^= (row>>1)&3 (= (l15>>1)&3 on reads since all row bases
// are multiples of 8). Applied on the pre-swizzled GLOBAL source; LDS dst linear.
template<int MODE>
__global__ __launch_bounds__(512, 2) void gemm8(
    const unsigned short* __restrict__ A, const unsigned short* __restrict__ Bmat,
    const float* __restrict__ bias0, const float* __restrict__ bias1,
    void* __restrict__ Cout)
{
  constexpr int NWG = (MODE == 0) ? 256 : 128;
  constexpr int NT = 32;  // 2048 / 64
  __shared__ char LDSb[131072];

  const int bid = blockIdx.x;
  const int id = (bid & 7) * (NWG / 8) + (bid >> 3);   // bijective XCD swizzle

  int mat, bx, by;
  if (MODE == 0)      { mat = id >> 7; int rem = id & 127; bx = rem & 7;  by = rem >> 3; }
  else if (MODE == 1) { mat = 0;       bx = id & 15; by = id >> 4; }
  else                { mat = 0;       bx = id & 7;  by = id >> 3; }

  const unsigned short* Ab = A + (long)(by * 256) * 2048;
  const unsigned short* Bb = ((MODE == 0) ? (Bmat + (long)mat * WN) : Bmat)
                             + (long)(bx * 256) * 2048;
  const float* bias = (MODE == 0 && mat) ? bias1 : bias0;

  const int t = threadIdx.x;
  const int wid = t >> 6, lane = t & 63;
  const int wr = wid >> 2, wc = wid & 3;
  const int l15 = lane & 15, lg = lane >> 4;

  // ---- staging addresses: chunk p in [0,1024) per half; row = p>>2, kc = p&3 ----
  const int p0 = t, p1 = t + 512;
  const int sw0 = ((p0 & 3) ^ ((p0 >> 3) & 3)) << 4;
  const int sw1 = ((p1 & 3) ^ ((p1 >> 3) & 3)) << 4;
  const char* srcA0 = (const char*)Ab + (long)(p0 >> 2) * 4096 + sw0;
  const char* srcA1 = (const char*)Ab + (long)(p1 >> 2) * 4096 + sw1;
  const char* srcB0 = (const char*)Bb + (long)(p0 >> 2) * 4096 + sw0;
  const char* srcB1 = (const char*)Bb + (long)(p1 >> 2) * 4096 + sw1;
  char* dA0 = LDSb + p0 * 16;
  char* dA1 = LDSb + p1 * 16;
  char* dB0 = LDSb + 16384 + p0 * 16;
  char* dB1 = LDSb + 16384 + p1 * 16;

  auto stage = [&](int buf, int kh, int tile) {
    const long go = (long)kh * 64 + (long)tile * 128;   // bytes along K
    const int lo = buf * 65536 + kh * 32768;
    gload_lds16(srcA0 + go, dA0 + lo);
    gload_lds16(srcA1 + go, dA1 + lo);
    gload_lds16(srcB0 + go, dB0 + lo);
    gload_lds16(srcB1 + go, dB1 + lo);
  };

  // ---- fragment read offsets ----
  const int koffL = ((lg ^ ((l15 >> 1) & 3)) << 4) + l15 * 64;  // lane part
  const int aBase0 = (wr * 128) * 64;          // + mh*64*64 + m*16*64
  const int bBase  = 16384 + (wc * 64) * 64;   // + n*16*64

  f32x4 acc[8][4];
  const f32x4 zero = {0.f, 0.f, 0.f, 0.f};
  #pragma unroll
  for (int m = 0; m < 8; m++)
    #pragma unroll
    for (int n = 0; n < 4; n++) acc[m][n] = zero;

  // prologue: h1(0), h2(0); wait for h1 (keep 4 in flight)
  stage(0, 0, 0);
  stage(0, 1, 0);
  asm volatile("s_waitcnt vmcnt(4)" ::: "memory");
  __builtin_amdgcn_s_barrier();
  __builtin_amdgcn_sched_barrier(0);

  int cur = 0;
  bf16x8 a0, a1, a2, a3, b0, b1, b2, b3;

  #define RD_A(buf, kh, mh) do {                                             \
    const char* p_ = LDSb + (buf) * 65536 + (kh) * 32768                     \
                     + aBase0 + (mh) * 4096 + koffL;                         \
    a0 = *(const bf16x8*)(p_);        a1 = *(const bf16x8*)(p_ + 1024);      \
    a2 = *(const bf16x8*)(p_ + 2048); a3 = *(const bf16x8*)(p_ + 3072); } while (0)
  #define RD_B(buf, kh) do {                                                 \
    const char* p_ = LDSb + (buf) * 65536 + (kh) * 32768 + bBase + koffL;    \
    b0 = *(const bf16x8*)(p_);        b1 = *(const bf16x8*)(p_ + 1024);      \
    b2 = *(const bf16x8*)(p_ + 2048); b3 = *(const bf16x8*)(p_ + 3072); } while (0)
  #define MFMA16(mo) do {                                                    \
    __builtin_amdgcn_s_setprio(1);                                           \
    acc[mo+0][0] = __builtin_amdgcn_mfma_f32_16x16x32_bf16(a0, b0, acc[mo+0][0],0,0,0); \
    acc[mo+0][1] = __builtin_amdgcn_mfma_f32_16x16x32_bf16(a0, b1, acc[mo+0][1],0,0,0); \
    acc[mo+0][2] = __builtin_amdgcn_mfma_f32_16x16x32_bf16(a0, b2, acc[mo+0][2],0,0,0); \
    acc[mo+0][3] = __builtin_amdgcn_mfma_f32_16x16x32_bf16(a0, b3, acc[mo+0][3],0,0,0); \
    acc[mo+1][0] = __builtin_amdgcn_mfma_f32_16x16x32_bf16(a1, b0, acc[mo+1][0],0,0,0); \
    acc[mo+1][1] = __builtin_amdgcn_mfma_f32_16x16x32_bf16(a1, b1, acc[mo+1][1],0,0,0); \
    acc[mo+1][2] = __builtin_amdgcn_mfma_f32_16x16x32_bf16(a1, b2, acc[mo+1][2],0,0,0); \
    acc[mo+1][3] = __builtin_amdgcn_mfma_f32_16x16x32_bf16(a1, b3, acc[mo+1][3],0,0,0); \
    acc[mo+2][0] = __builtin_amdgcn_mfma_f32_16x16x32_bf16(a2, b0, acc[mo+2][0],0,0,0); \
    acc[mo+2][1] = __builtin_amdgcn_mfma_f32_16x16x32_bf16(a2, b1, acc[mo+2][1],0,0,0); \
    acc[mo+2][2] = __builtin_amdgcn_mfma_f32_16x16x32_bf16(a2, b2, acc[mo+2][2],0,0,0); \
    acc[mo+2][3] = __builtin_amdgcn_mfma_f32_16x16x32_bf16(a2, b3, acc[mo+2][3],0,0,0); \
    acc[mo+3][0] = __builtin_amdgcn_mfma_f32_16x16x32_bf16(a3, b0, acc[mo+3][0],0,0,0); \
    acc[mo+3][1] = __builtin_amdgcn_mfma_f32_16x16x32_bf16(a3, b1, acc[mo+3][1],0,0,0); \
    acc[mo+3][2] = __builtin_amdgcn_mfma_f32_16x16x32_bf16(a3, b2, acc[mo+3][2],0,0,0); \
    acc[mo+3][3] = __builtin_amdgcn_mfma_f32_16x16x32_bf16(a3, b3, acc[mo+3][3],0,0,0); \
    __builtin_amdgcn_s_setprio(0); } while (0)

  for (int tt = 0; tt < NT - 1; tt++) {
    const int nxt = cur ^ 1;
    // P1
    stage(nxt, 0, tt + 1);
    RD_B(cur, 0); RD_A(cur, 0, 0);
    MFMA16(0);
    __builtin_amdgcn_s_barrier();
    __builtin_amdgcn_sched_barrier(0);
    // P2
    RD_A(cur, 0, 1);
    MFMA16(4);
    asm volatile("s_waitcnt vmcnt(4)" ::: "memory");   // h2(tt) landed
    __builtin_amdgcn_s_barrier();
    __builtin_amdgcn_sched_barrier(0);
    // P3
    stage(nxt, 1, tt + 1);
    RD_B(cur, 1); RD_A(cur, 1, 0);
    MFMA16(0);
    __builtin_amdgcn_s_barrier();
    __builtin_amdgcn_sched_barrier(0);
    // P4
    RD_A(cur, 1, 1);
    MFMA16(4);
    asm volatile("s_waitcnt vmcnt(4)" ::: "memory");   // h1(tt+1) landed
    __builtin_amdgcn_s_barrier();
    __builtin_amdgcn_sched_barrier(0);
    cur = nxt;
  }
  // tail tile NT-1 (no staging; h2 still in flight at entry)
  {
    RD_B(cur, 0); RD_A(cur, 0, 0);
    MFMA16(0);
    __builtin_amdgcn_s_barrier();
    __builtin_amdgcn_sched_barrier(0);
    RD_A(cur, 0, 1);
    MFMA16(4);
    asm volatile("s_waitcnt vmcnt(0)" ::: "memory");   // h2 landed (tail drain)
    __builtin_amdgcn_s_barrier();
    __builtin_amdgcn_sched_barrier(0);
    RD_B(cur, 1); RD_A(cur, 1, 0);
    MFMA16(0);
    RD_A(cur, 1, 1);
    MFMA16(4);
  }
  #undef RD_A
  #undef RD_B
  #undef MFMA16

  // ---- epilogue ----
  #pragma unroll
  for (int am = 0; am < 8; am++) {
    const int row = by * 256 + wr * 128 + am * 16 + lg * 4;
    #pragma unroll
    for (int n = 0; n < 4; n++) {
      const int col = bx * 256 + wc * 64 + n * 16 + l15;
      #pragma unroll
      for (int r = 0; r < 4; r++) {
        float v = acc[am][n][r];
        if (MODE == 0) {
          v += bias[col];
          ((unsigned short*)Cout + (long)mat * XN)[(long)(row + r) * 2048 + col] = f2bf(v);
        } else if (MODE == 1) {
          v += bias[row + r];
          ((unsigned short*)Cout)[(long)(row + r) * 2048 + (col & 2047)
                                  + (long)(col >> 11) * 4194304] = f2bf(v);
        } else {
          v += bias[col];
          ((float*)Cout)[(long)(row + r) * 2048 + col] = v;
        }
      }
    }
  }
}

// ---------------- 4) per-(row,head) L2 norm of Q (x scale) and K ----------------
__global__ __launch_bounds__(256) void norm_qk(unsigned short* __restrict__ Q,
                                               unsigned short* __restrict__ Kb,
                                               const float* __restrict__ scale_p)
{
  const int w = threadIdx.x >> 6, lane = threadIdx.x & 63;
  const long id = (long)blockIdx.x * 4 + w;
  const int isK = id >= 65536;
  const long p = isK ? id - 65536 : id;
  unsigned short* base = (isK ? Kb : Q) + (p >> 4) * 2048 + (p & 15) * 128 + lane * 2;
  unsigned int v = *(const unsigned int*)base;
  float x0 = bf2f((unsigned short)(v & 0xffffu));
  float x1 = bf2f((unsigned short)(v >> 16));
  float ss = x0 * x0 + x1 * x1;
  ss += __shfl_xor(ss, 1);  ss += __shfl_xor(ss, 2);  ss += __shfl_xor(ss, 4);
  ss += __shfl_xor(ss, 8);  ss += __shfl_xor(ss, 16); ss += __shfl_xor(ss, 32);
  float inv = rsqrtf(fmaxf(ss, 1e-24f));
  if (!isK) inv *= *scale_p;
  unsigned int o = (unsigned int)f2bf(x0 * inv) | ((unsigned int)f2bf(x1 * inv) << 16);
  *(unsigned int*)base = o;
}

// ---------------- 5) fused cosine attention (v3, unchanged) ----------------
__global__ __launch_bounds__(256, 2) void attn_kernel(
    const unsigned short* __restrict__ Q,
    const unsigned short* __restrict__ Kg_,
    const unsigned short* __restrict__ Vt_,
    const float* __restrict__ biasArr,
    unsigned short* __restrict__ ctx)
{
  __shared__ unsigned char KS[16384];
  __shared__ unsigned char VS[16384];
  __shared__ unsigned short Pl[4][32][72];

  const int bh = blockIdx.y, b = bh >> 4, h = bh & 15;
  const int t = threadIdx.x, w = t >> 6, lane = t & 63;
  const int l15 = lane & 15, lg = lane >> 4;
  const int xork = (l15 & 7) << 4;
  const int qrow0 = blockIdx.x * 128 + w * 32;

  bf16x8 aq[2][4];
  #pragma unroll
  for (int m = 0; m < 2; m++)
    #pragma unroll
    for (int dk = 0; dk < 4; dk++)
      aq[m][dk] = *(const bf16x8*)&Q[(long)(b * 2048 + qrow0 + m * 16 + l15) * 2048
                                     + h * 128 + dk * 32 + lg * 8];

  const char* Kgp = (const char*)(Kg_ + (long)b * 2048 * 2048 + h * 128);
  const char* Vgp = (const char*)(Vt_ + (long)bh * 128 * 2048);
  const int rK = t >> 4;
  const int rV = t >> 3;
  const char* srcK0 = Kgp + (long)rK * 4096 + (((t & 15) * 16) ^ ((rK & 7) << 4));
  const char* srcV0 = Vgp + (long)rV * 4096 + (((t & 7) * 16) ^ ((rV & 7) << 4));
  char* dstK0 = (char*)KS + t * 16;
  char* dstV0 = (char*)VS + t * 16;

  f32x4 o[2][8]; float den[2][4];
  const f32x4 zero = {0.f, 0.f, 0.f, 0.f};
  #pragma unroll
  for (int m = 0; m < 2; m++) {
    #pragma unroll
    for (int df = 0; df < 8; df++) o[m][df] = zero;
    #pragma unroll
    for (int r = 0; r < 4; r++) den[m][r] = 0.f;
  }

  const char* KSc = (const char*)KS;
  const char* VSc = (const char*)VS;
  int cK[4], cV2[2];
  #pragma unroll
  for (int dk = 0; dk < 4; dk++) cK[dk] = (dk * 64 + lg * 16) ^ xork;
  #pragma unroll
  for (int kk = 0; kk < 2; kk++) cV2[kk] = (kk * 64 + lg * 16) ^ xork;
  const int rowK = l15 * 256, rowV = l15 * 128;

  #pragma unroll
  for (int i = 0; i < 4; i++) gload_lds16(srcK0 + i * 65536,  dstK0 + i * 4096);
  #pragma unroll
  for (int i = 0; i < 4; i++) gload_lds16(srcV0 + i * 131072, dstV0 + i * 4096);

  const float* brow = biasArr + b * 2048 + l15;
  const float L2E = 1.44269504088896f;

  for (int kt = 0; kt < 32; kt++) {
    const int k0 = kt * 64;
    asm volatile("s_waitcnt vmcnt(4)" ::: "memory");
    __builtin_amdgcn_s_barrier();
    __builtin_amdgcn_sched_barrier(0);

    float bn[4];
    #pragma unroll
    for (int n = 0; n < 4; n++) bn[n] = brow[k0 + n * 16];

    f32x4 s[2][4];
    #pragma unroll
    for (int m = 0; m < 2; m++)
      #pragma unroll
      for (int n = 0; n < 4; n++) s[m][n] = zero;
    __builtin_amdgcn_s_setprio(1);
    #pragma unroll
    for (int n = 0; n < 4; n++) {
      #pragma unroll
      for (int dk = 0; dk < 4; dk++) {
        bf16x8 bk = *(const bf16x8*)(KSc + n * 4096 + rowK + cK[dk]);
        s[0][n] = __builtin_amdgcn_mfma_f32_16x16x32_bf16(aq[0][dk], bk, s[0][n], 0, 0, 0);
        s[1][n] = __builtin_amdgcn_mfma_f32_16x16x32_bf16(aq[1][dk], bk, s[1][n], 0, 0, 0);
      }
    }
    __builtin_amdgcn_s_setprio(0);

    #pragma unroll
    for (int n = 0; n < 4; n++) {
      #pragma unroll
      for (int m = 0; m < 2; m++) {
        #pragma unroll
        for (int r = 0; r < 4; r++) {
          float e = exp2f(fmaf(s[m][n][r], L2E, bn[n]));
          den[m][r] += e;
          Pl[w][m * 16 + lg * 4 + r][n * 16 + l15] = f2bf(e);
        }
      }
    }

    asm volatile("s_waitcnt vmcnt(0)" ::: "memory");
    __builtin_amdgcn_s_barrier();
    __builtin_amdgcn_sched_barrier(0);
    if (kt < 31) {
      const long kof = (long)(kt + 1) * 262144;
      #pragma unroll
      for (int i = 0; i < 4; i++) gload_lds16(srcK0 + kof + i * 65536, dstK0 + i * 4096);
    }

    #pragma unroll
    for (int kk = 0; kk < 2; kk++) {
      bf16x8 ap0 = *(const bf16x8*)&Pl[w][l15][kk * 32 + lg * 8];
      bf16x8 ap1 = *(const bf16x8*)&Pl[w][16 + l15][kk * 32 + lg * 8];
      bf16x8 bv[8];
      #pragma unroll
      for (int df = 0; df < 8; df++)
        bv[df] = *(const bf16x8*)(VSc + df * 2048 + rowV + cV2[kk]);
      __builtin_amdgcn_s_setprio(1);
      #pragma unroll
      for (int df = 0; df < 8; df++) {
        o[0][df] = __builtin_amdgcn_mfma_f32_16x16x32_bf16(ap0, bv[df], o[0][df], 0, 0, 0);
        o[1][df] = __builtin_amdgcn_mfma_f32_16x16x32_bf16(ap1, bv[df], o[1][df], 0, 0, 0);
      }
      __builtin_amdgcn_s_setprio(0);
    }

    __builtin_amdgcn_s_barrier();
    __builtin_amdgcn_sched_barrier(0);
    if (kt < 31) {
      const long vof = (long)(kt + 1) * 128;
      #pragma unroll
      for (int i = 0; i < 4; i++) gload_lds16(srcV0 + vof + i * 131072, dstV0 + i * 4096);
    }
  }

  #pragma unroll
  for (int m = 0; m < 2; m++)
    #pragma unroll
    for (int r = 0; r < 4; r++) {
      float d = den[m][r];
      d += __shfl_xor(d, 1); d += __shfl_xor(d, 2);
      d += __shfl_xor(d, 4); d += __shfl_xor(d, 8);
      den[m][r] = 1.0f / d;
    }
  #pragma unroll
  for (int m = 0; m < 2; m++) {
    const long row = b * 2048 + qrow0 + m * 16 + lg * 4;
    #pragma unroll
    for (int df = 0; df < 8; df++) {
      const int col = h * 128 + df * 16 + l15;
      #pragma unroll
      for (int r = 0; r < 4; r++)
        ctx[(row + r) * 2048 + col] = f2bf(o[m][df][r] * den[m][r]);
    }
  }
}

// ---------------- launch ----------------
extern "C" void kernel_launch(void* const* d_in, const int* in_sizes, int n_in,
                              void* d_out, int out_size, void* d_ws, size_t ws_size,
                              hipStream_t stream) {
  const float* x    = (const float*)d_in[0];
  const int*   mask = (const int*)d_in[1];
  const float* Wq   = (const float*)d_in[2];
  const float* bq   = (const float*)d_in[3];
  const float* Wk   = (const float*)d_in[4];
  const float* bk   = (const float*)d_in[5];
  const float* Wv   = (const float*)d_in[6];
  const float* bv   = (const float*)d_in[7];
  const float* Wo   = (const float*)d_in[8];
  const float* bo   = (const float*)d_in[9];
  const float* asc  = (const float*)d_in[10];
  float* out = (float*)d_out;

  unsigned short* w   = (unsigned short*)d_ws;
  unsigned short* Xb  = w;
  unsigned short* Wqb = Xb  + XN;   // Wkb = Wqb + WN (contiguous, used by gemm8<0>)
  unsigned short* Wvb = Wqb + 2 * WN;
  unsigned short* Wob = Wvb + WN;
  unsigned short* Qb  = Wob + WN;
  unsigned short* Kbf = Qb  + XN;
  unsigned short* Vt  = Kbf + XN;
  float*          Bias = (float*)(Vt + XN);
  unsigned short* Ctx = Xb;   // alias: X dead after Q/K/Vt GEMMs

  cast5_kernel<<<2048, 256, 0, stream>>>(x, Wq, Wk, Wv, Wo, Xb, mask, Bias);

  gemm8<0><<<256, 512, 0, stream>>>(Xb, Wqb, bq, bk, Qb);    // Q and K
  gemm8<1><<<128, 512, 0, stream>>>(Wvb, Xb, bv, bv, Vt);    // Vt = (X Wv^T)^T

  norm_qk<<<32768, 256, 0, stream>>>(Qb, Kbf, asc);

  attn_kernel<<<dim3(16, 32), 256, 0, stream>>>(Qb, Kbf, Vt, Bias, Ctx);

  gemm8<2><<<128, 512, 0, stream>>>(Ctx, Wob, bo, bo, out);
}

// Round 6
// 416.714 us; speedup vs baseline: 1.6188x; 1.0807x over previous
//
#include <hip/hip_runtime.h>
#include <hip/hip_bf16.h>
#include <stdint.h>

// MultiHeadAttention_79714593013958 — cosine-normalized MHA, MI355X bf16 MFMA pipeline.
// bs=2, qlen=2048, dim=2048, heads=16, dph=128.
//
//  1) cast5:     X, Wq, Wk, Wv, Wo f32->bf16 ; mask -> additive bias (0 / -1e5)
//  2) gemm8<0>:  Q,K = X @ {Wq,Wk}^T + b   (256 wgs, 256x256, 8-barrier phases)
//  3) gemm8<1>:  Vt = Wv @ X^T (+bv row)   (256 wgs, 256x128, full GPU)
//  4) norm_qk:   per-(row,head) L2 normalize Q (xscale) and K in place
//  5) attn:      LDS-staged K/V tiles, counted-vmcnt pipeline (v3, unchanged)
//  6) gemm8<2>:  out = ctx @ Wo^T + bo     (256 wgs, 256x128, f32)

typedef __attribute__((ext_vector_type(8))) short bf16x8;
typedef __attribute__((ext_vector_type(4))) float f32x4;
typedef __attribute__((ext_vector_type(8))) unsigned short u16x8;

#define XN 8388608L   // 2*2048*2048
#define WN 4194304L   // 2048*2048

__device__ __forceinline__ float bf2f(unsigned short u) {
  union { unsigned int i; float f; } v; v.i = ((unsigned int)u) << 16; return v.f;
}
__device__ __forceinline__ unsigned short f2bf(float f) {
  union { float f; unsigned int i; } u; u.f = f;
  unsigned int r = u.i + 0x7FFFu + ((u.i >> 16) & 1u);
  return (unsigned short)(r >> 16);
}

__device__ __forceinline__ void gload_lds16(const void* g, void* l) {
  __builtin_amdgcn_global_load_lds((__attribute__((address_space(1))) void*)g,
                                   (__attribute__((address_space(3))) void*)l,
                                   16, 0, 0);
}

// ---------------- 1) f32 -> bf16 cast of X + 4 weights, mask -> bias ----------------
__global__ __launch_bounds__(256) void cast5_kernel(
    const float* __restrict__ x,  const float* __restrict__ w0,
    const float* __restrict__ w1, const float* __restrict__ w2,
    const float* __restrict__ w3, unsigned short* __restrict__ dst,
    const int* __restrict__ mask, float* __restrict__ biasf)
{
  const long total8 = (XN + 4 * WN) >> 3;
  const long tid0 = (long)blockIdx.x * blockDim.x + threadIdx.x;
  const long stride = (long)gridDim.x * blockDim.x;
  for (long i = tid0; i < total8; i += stride) {
    long e = i << 3;
    const float* src; long off;
    if (e < XN) { src = x; off = e; }
    else {
      long r = e - XN;
      int wi = (int)(r >> 22);
      off = r & (WN - 1);
      src = (wi == 0) ? w0 : (wi == 1) ? w1 : (wi == 2) ? w2 : w3;
    }
    const float4* p = (const float4*)(src + off);
    float4 a = p[0], b = p[1];
    u16x8 o;
    o[0] = f2bf(a.x); o[1] = f2bf(a.y); o[2] = f2bf(a.z); o[3] = f2bf(a.w);
    o[4] = f2bf(b.x); o[5] = f2bf(b.y); o[6] = f2bf(b.z); o[7] = f2bf(b.w);
    *(u16x8*)(dst + e) = o;
  }
  for (long j = tid0; j < 4096; j += stride)
    biasf[j] = (mask[j] != 0) ? 0.f : -1.0e5f;
}

// ---------------- 2/3/6) counted-vmcnt phased BT-GEMM, K=2048 ----------------
// MODE 0: BM=256,BN=256, 8 waves 2Mx4N (128x64/wave, acc[8][4]), 256 wgs.
//   Per K-tile (BK=64 as 2 kh-halves): 4 phases x {reads; [stage]; barrier;
//   lgkmcnt(0); 16 MFMA; [vmcnt(4)]; barrier}. Ledger: 8->4->8->4.
// MODE 1/2: BM=256,BN=128, 8 waves 4Mx2N (64x64/wave, acc[4][4]), 256 wgs.
//   2 phases/K-tile, 3 loads/stage, vmcnt(3) each phase. Ledger: 6->3->6->3.
// Swizzle: 16B slot s of row stores global chunk s ^ ((row>>1)&3); applied on
// the GLOBAL source (LDS dst linear), un-applied identically on ds_read.
template<int MODE>
__global__ __launch_bounds__(512, 2) void gemm8(
    const unsigned short* __restrict__ A, const unsigned short* __restrict__ Bmat,
    const float* __restrict__ bias0, const float* __restrict__ bias1,
    void* __restrict__ Cout)
{
  constexpr int NWG = 256;
  constexpr int NT  = 32;                          // 2048 / 64
  constexpr int KHS = (MODE == 0) ? 32768 : 24576; // bytes per (buf,kh) block
  constexpr int BUFS = 2 * KHS;
  __shared__ char LDSb[(MODE == 0) ? 131072 : 98304];

  const int bid = blockIdx.x;
  const int id = (bid & 7) * (NWG / 8) + (bid >> 3);   // bijective XCD swizzle

  int mat, bx, by;
  if (MODE == 0)      { mat = id >> 7; int rem = id & 127; bx = rem & 7;  by = rem >> 3; }
  else if (MODE == 1) { mat = 0; bx = id & 31; by = id >> 5; }
  else                { mat = 0; bx = id & 15; by = id >> 4; }

  constexpr int BN = (MODE == 0) ? 256 : 128;
  const unsigned short* Ab = A + (long)(by * 256) * 2048;
  const unsigned short* Bb = ((MODE == 0) ? (Bmat + (long)mat * WN) : Bmat)
                             + (long)(bx * BN) * 2048;
  const float* bias = (MODE == 0 && mat) ? bias1 : bias0;

  const int t = threadIdx.x;
  const int wid = t >> 6, lane = t & 63;
  const int wr = (MODE == 0) ? (wid >> 2) : (wid >> 1);
  const int wc = (MODE == 0) ? (wid & 3)  : (wid & 1);
  const int l15 = lane & 15, lg = lane >> 4;

  // ---- staging: chunk p -> row p>>2, slot p&3; src pre-swizzled, dst linear ----
  const int pA0 = t, pA1 = t + 512;
  auto sw = [](int p) { return (((p & 3) ^ ((p >> 3) & 3)) << 4); };
  const char* srcA0 = (const char*)Ab + (long)(pA0 >> 2) * 4096 + sw(pA0);
  const char* srcA1 = (const char*)Ab + (long)(pA1 >> 2) * 4096 + sw(pA1);
  const char* srcB0 = (const char*)Bb + (long)(pA0 >> 2) * 4096 + sw(pA0);
  const char* srcB1 = (const char*)Bb + (long)(pA1 >> 2) * 4096 + sw(pA1);  // MODE0 only

  auto stage = [&](int buf, int kh, int tile) {
    const long go = (long)tile * 128 + kh * 64;
    char* base = LDSb + buf * BUFS + kh * KHS;
    gload_lds16(srcA0 + go, base + pA0 * 16);
    gload_lds16(srcA1 + go, base + pA1 * 16);
    if (MODE == 0) {
      gload_lds16(srcB0 + go, base + 16384 + pA0 * 16);
      gload_lds16(srcB1 + go, base + 16384 + pA1 * 16);
    } else {
      gload_lds16(srcB0 + go, base + 16384 + t * 16);
    }
  };

  // ---- fragment read offsets ----
  const int slot16 = ((lg ^ ((l15 >> 1) & 3)) << 4);
  const int aRowOff = ((MODE == 0) ? (wr * 128) : (wr * 64)) * 64 + l15 * 64 + slot16;
  const int bColOff = 16384 + (wc * 64) * 64 + l15 * 64 + slot16;

  constexpr int AM = (MODE == 0) ? 8 : 4;
  f32x4 acc[AM][4];
  const f32x4 zero = {0.f, 0.f, 0.f, 0.f};
  #pragma unroll
  for (int m = 0; m < AM; m++)
    #pragma unroll
    for (int n = 0; n < 4; n++) acc[m][n] = zero;

  bf16x8 a_[4], b_[4];

  #define RD_A(buf, kh, mh) do {                                              \
    const char* p_ = LDSb + (buf) * BUFS + (kh) * KHS + aRowOff + (mh) * 4096;\
    a_[0] = *(const bf16x8*)(p_);        a_[1] = *(const bf16x8*)(p_ + 1024); \
    a_[2] = *(const bf16x8*)(p_ + 2048); a_[3] = *(const bf16x8*)(p_ + 3072); } while (0)
  #define RD_B(buf, kh) do {                                                  \
    const char* p_ = LDSb + (buf) * BUFS + (kh) * KHS + bColOff;              \
    b_[0] = *(const bf16x8*)(p_);        b_[1] = *(const bf16x8*)(p_ + 1024); \
    b_[2] = *(const bf16x8*)(p_ + 2048); b_[3] = *(const bf16x8*)(p_ + 3072); } while (0)
  #define CL(amB) do {                                                        \
    __builtin_amdgcn_s_setprio(1);                                            \
    _Pragma("unroll")                                                         \
    for (int i_ = 0; i_ < 4; i_++)                                            \
      _Pragma("unroll")                                                       \
      for (int n_ = 0; n_ < 4; n_++)                                          \
        acc[(amB) + i_][n_] = __builtin_amdgcn_mfma_f32_16x16x32_bf16(        \
            a_[i_], b_[n_], acc[(amB) + i_][n_], 0, 0, 0);                    \
    __builtin_amdgcn_s_setprio(0); } while (0)
  #define SB0   __builtin_amdgcn_sched_barrier(0)
  #define BAR   __builtin_amdgcn_s_barrier()
  #define LGKM0 asm volatile("s_waitcnt lgkmcnt(0)" ::: "memory")
  #define VMW(n) asm volatile("s_waitcnt vmcnt(" #n ")" ::: "memory")

  // ---- prologue: both halves of tile 0 ----
  stage(0, 0, 0);
  stage(0, 1, 0);
  if (MODE == 0) VMW(4); else VMW(3);
  BAR; SB0;

  int cur = 0;
  for (int tt = 0; tt < NT - 1; tt++) {
    const int nxt = cur ^ 1;
    if (MODE == 0) {
      // P1: reads kh0 (A mh0 + B); stage h1(t+1)
      RD_A(cur, 0, 0); RD_B(cur, 0);
      stage(nxt, 0, tt + 1);
      SB0; BAR; LGKM0; SB0;
      CL(0);
      BAR;
      // P2: reads A mh1 kh0 (B persists)
      RD_A(cur, 0, 1);
      SB0; BAR; LGKM0; SB0;
      CL(4);
      VMW(4);   // h2(t) landed (needed by P3 reads)
      BAR;
      // P3: reads kh1 (A mh0 + B); stage h2(t+1)
      RD_A(cur, 1, 0); RD_B(cur, 1);
      stage(nxt, 1, tt + 1);
      SB0; BAR; LGKM0; SB0;
      CL(0);
      BAR;
      // P4: reads A mh1 kh1
      RD_A(cur, 1, 1);
      SB0; BAR; LGKM0; SB0;
      CL(4);
      VMW(4);   // h1(t+1) landed (needed by next P1)
      BAR;
    } else {
      // P1: kh0
      RD_A(cur, 0, 0); RD_B(cur, 0);
      stage(nxt, 0, tt + 1);
      SB0; BAR; LGKM0; SB0;
      CL(0);
      VMW(3);   // h2(t) landed
      BAR;
      // P2: kh1
      RD_A(cur, 1, 0); RD_B(cur, 1);
      stage(nxt, 1, tt + 1);
      SB0; BAR; LGKM0; SB0;
      CL(0);
      VMW(3);   // h1(t+1) landed
      BAR;
    }
    cur = nxt;
  }
  // ---- tail tile (no staging) ----
  if (MODE == 0) {
    RD_A(cur, 0, 0); RD_B(cur, 0);
    SB0; BAR; LGKM0; SB0;
    CL(0);
    BAR;
    RD_A(cur, 0, 1);
    SB0; BAR; LGKM0; SB0;
    CL(4);
    VMW(0);   // h2 landed
    BAR;
    RD_A(cur, 1, 0); RD_B(cur, 1);
    SB0; BAR; LGKM0; SB0;
    CL(0);
    BAR;
    RD_A(cur, 1, 1);
    SB0; LGKM0; SB0;
    CL(4);
  } else {
    RD_A(cur, 0, 0); RD_B(cur, 0);
    SB0; BAR; LGKM0; SB0;
    CL(0);
    VMW(0);   // h2 landed
    BAR;
    RD_A(cur, 1, 0); RD_B(cur, 1);
    SB0; LGKM0; SB0;
    CL(0);
  }
  #undef RD_A
  #undef RD_B
  #undef CL
  #undef SB0
  #undef BAR
  #undef LGKM0
  #undef VMW

  // ---- epilogue ----
  const int rowW = (MODE == 0) ? (wr * 128) : (wr * 64);
  #pragma unroll
  for (int am = 0; am < AM; am++) {
    const int row = by * 256 + rowW + am * 16 + lg * 4;
    #pragma unroll
    for (int n = 0; n < 4; n++) {
      const int col = bx * BN + wc * 64 + n * 16 + l15;
      #pragma unroll
      for (int r = 0; r < 4; r++) {
        float v = acc[am][n][r];
        if (MODE == 0) {
          v += bias[col];
          ((unsigned short*)Cout + (long)mat * XN)[(long)(row + r) * 2048 + col] = f2bf(v);
        } else if (MODE == 1) {
          v += bias[row + r];
          ((unsigned short*)Cout)[(long)(row + r) * 2048 + (col & 2047)
                                  + (long)(col >> 11) * 4194304] = f2bf(v);
        } else {
          v += bias[col];
          ((float*)Cout)[(long)(row + r) * 2048 + col] = v;
        }
      }
    }
  }
}

// ---------------- 4) per-(row,head) L2 norm of Q (x scale) and K ----------------
__global__ __launch_bounds__(256) void norm_qk(unsigned short* __restrict__ Q,
                                               unsigned short* __restrict__ Kb,
                                               const float* __restrict__ scale_p)
{
  const int w = threadIdx.x >> 6, lane = threadIdx.x & 63;
  const long id = (long)blockIdx.x * 4 + w;
  const int isK = id >= 65536;
  const long p = isK ? id - 65536 : id;
  unsigned short* base = (isK ? Kb : Q) + (p >> 4) * 2048 + (p & 15) * 128 + lane * 2;
  unsigned int v = *(const unsigned int*)base;
  float x0 = bf2f((unsigned short)(v & 0xffffu));
  float x1 = bf2f((unsigned short)(v >> 16));
  float ss = x0 * x0 + x1 * x1;
  ss += __shfl_xor(ss, 1);  ss += __shfl_xor(ss, 2);  ss += __shfl_xor(ss, 4);
  ss += __shfl_xor(ss, 8);  ss += __shfl_xor(ss, 16); ss += __shfl_xor(ss, 32);
  float inv = rsqrtf(fmaxf(ss, 1e-24f));
  if (!isK) inv *= *scale_p;
  unsigned int o = (unsigned int)f2bf(x0 * inv) | ((unsigned int)f2bf(x1 * inv) << 16);
  *(unsigned int*)base = o;
}

// ---------------- 5) fused cosine attention (v3, unchanged) ----------------
__global__ __launch_bounds__(256, 2) void attn_kernel(
    const unsigned short* __restrict__ Q,
    const unsigned short* __restrict__ Kg_,
    const unsigned short* __restrict__ Vt_,
    const float* __restrict__ biasArr,
    unsigned short* __restrict__ ctx)
{
  __shared__ unsigned char KS[16384];
  __shared__ unsigned char VS[16384];
  __shared__ unsigned short Pl[4][32][72];

  const int bh = blockIdx.y, b = bh >> 4, h = bh & 15;
  const int t = threadIdx.x, w = t >> 6, lane = t & 63;
  const int l15 = lane & 15, lg = lane >> 4;
  const int xork = (l15 & 7) << 4;
  const int qrow0 = blockIdx.x * 128 + w * 32;

  bf16x8 aq[2][4];
  #pragma unroll
  for (int m = 0; m < 2; m++)
    #pragma unroll
    for (int dk = 0; dk < 4; dk++)
      aq[m][dk] = *(const bf16x8*)&Q[(long)(b * 2048 + qrow0 + m * 16 + l15) * 2048
                                     + h * 128 + dk * 32 + lg * 8];

  const char* Kgp = (const char*)(Kg_ + (long)b * 2048 * 2048 + h * 128);
  const char* Vgp = (const char*)(Vt_ + (long)bh * 128 * 2048);
  const int rK = t >> 4;
  const int rV = t >> 3;
  const char* srcK0 = Kgp + (long)rK * 4096 + (((t & 15) * 16) ^ ((rK & 7) << 4));
  const char* srcV0 = Vgp + (long)rV * 4096 + (((t & 7) * 16) ^ ((rV & 7) << 4));
  char* dstK0 = (char*)KS + t * 16;
  char* dstV0 = (char*)VS + t * 16;

  f32x4 o[2][8]; float den[2][4];
  const f32x4 zero = {0.f, 0.f, 0.f, 0.f};
  #pragma unroll
  for (int m = 0; m < 2; m++) {
    #pragma unroll
    for (int df = 0; df < 8; df++) o[m][df] = zero;
    #pragma unroll
    for (int r = 0; r < 4; r++) den[m][r] = 0.f;
  }

  const char* KSc = (const char*)KS;
  const char* VSc = (const char*)VS;
  int cK[4], cV2[2];
  #pragma unroll
  for (int dk = 0; dk < 4; dk++) cK[dk] = (dk * 64 + lg * 16) ^ xork;
  #pragma unroll
  for (int kk = 0; kk < 2; kk++) cV2[kk] = (kk * 64 + lg * 16) ^ xork;
  const int rowK = l15 * 256, rowV = l15 * 128;

  #pragma unroll
  for (int i = 0; i < 4; i++) gload_lds16(srcK0 + i * 65536,  dstK0 + i * 4096);
  #pragma unroll
  for (int i = 0; i < 4; i++) gload_lds16(srcV0 + i * 131072, dstV0 + i * 4096);

  const float* brow = biasArr + b * 2048 + l15;
  const float L2E = 1.44269504088896f;

  for (int kt = 0; kt < 32; kt++) {
    const int k0 = kt * 64;
    asm volatile("s_waitcnt vmcnt(4)" ::: "memory");
    __builtin_amdgcn_s_barrier();
    __builtin_amdgcn_sched_barrier(0);

    float bn[4];
    #pragma unroll
    for (int n = 0; n < 4; n++) bn[n] = brow[k0 + n * 16];

    f32x4 s[2][4];
    #pragma unroll
    for (int m = 0; m < 2; m++)
      #pragma unroll
      for (int n = 0; n < 4; n++) s[m][n] = zero;
    __builtin_amdgcn_s_setprio(1);
    #pragma unroll
    for (int n = 0; n < 4; n++) {
      #pragma unroll
      for (int dk = 0; dk < 4; dk++) {
        bf16x8 bk = *(const bf16x8*)(KSc + n * 4096 + rowK + cK[dk]);
        s[0][n] = __builtin_amdgcn_mfma_f32_16x16x32_bf16(aq[0][dk], bk, s[0][n], 0, 0, 0);
        s[1][n] = __builtin_amdgcn_mfma_f32_16x16x32_bf16(aq[1][dk], bk, s[1][n], 0, 0, 0);
      }
    }
    __builtin_amdgcn_s_setprio(0);

    #pragma unroll
    for (int n = 0; n < 4; n++) {
      #pragma unroll
      for (int m = 0; m < 2; m++) {
        #pragma unroll
        for (int r = 0; r < 4; r++) {
          float e = exp2f(fmaf(s[m][n][r], L2E, bn[n]));
          den[m][r] += e;
          Pl[w][m * 16 + lg * 4 + r][n * 16 + l15] = f2bf(e);
        }
      }
    }

    asm volatile("s_waitcnt vmcnt(0)" ::: "memory");
    __builtin_amdgcn_s_barrier();
    __builtin_amdgcn_sched_barrier(0);
    if (kt < 31) {
      const long kof = (long)(kt + 1) * 262144;
      #pragma unroll
      for (int i = 0; i < 4; i++) gload_lds16(srcK0 + kof + i * 65536, dstK0 + i * 4096);
    }

    #pragma unroll
    for (int kk = 0; kk < 2; kk++) {
      bf16x8 ap0 = *(const bf16x8*)&Pl[w][l15][kk * 32 + lg * 8];
      bf16x8 ap1 = *(const bf16x8*)&Pl[w][16 + l15][kk * 32 + lg * 8];
      bf16x8 bv[8];
      #pragma unroll
      for (int df = 0; df < 8; df++)
        bv[df] = *(const bf16x8*)(VSc + df * 2048 + rowV + cV2[kk]);
      __builtin_amdgcn_s_setprio(1);
      #pragma unroll
      for (int df = 0; df < 8; df++) {
        o[0][df] = __builtin_amdgcn_mfma_f32_16x16x32_bf16(ap0, bv[df], o[0][df], 0, 0, 0);
        o[1][df] = __builtin_amdgcn_mfma_f32_16x16x32_bf16(ap1, bv[df], o[1][df], 0, 0, 0);
      }
      __builtin_amdgcn_s_setprio(0);
    }

    __builtin_amdgcn_s_barrier();
    __builtin_amdgcn_sched_barrier(0);
    if (kt < 31) {
      const long vof = (long)(kt + 1) * 128;
      #pragma unroll
      for (int i = 0; i < 4; i++) gload_lds16(srcV0 + vof + i * 131072, dstV0 + i * 4096);
    }
  }

  #pragma unroll
  for (int m = 0; m < 2; m++)
    #pragma unroll
    for (int r = 0; r < 4; r++) {
      float d = den[m][r];
      d += __shfl_xor(d, 1); d += __shfl_xor(d, 2);
      d += __shfl_xor(d, 4); d += __shfl_xor(d, 8);
      den[m][r] = 1.0f / d;
    }
  #pragma unroll
  for (int m = 0; m < 2; m++) {
    const long row = b * 2048 + qrow0 + m * 16 + lg * 4;
    #pragma unroll
    for (int df = 0; df < 8; df++) {
      const int col = h * 128 + df * 16 + l15;
      #pragma unroll
      for (int r = 0; r < 4; r++)
        ctx[(row + r) * 2048 + col] = f2bf(o[m][df][r] * den[m][r]);
    }
  }
}

// ---------------- launch ----------------
extern "C" void kernel_launch(void* const* d_in, const int* in_sizes, int n_in,
                              void* d_out, int out_size, void* d_ws, size_t ws_size,
                              hipStream_t stream) {
  const float* x    = (const float*)d_in[0];
  const int*   mask = (const int*)d_in[1];
  const float* Wq   = (const float*)d_in[2];
  const float* bq   = (const float*)d_in[3];
  const float* Wk   = (const float*)d_in[4];
  const float* bk   = (const float*)d_in[5];
  const float* Wv   = (const float*)d_in[6];
  const float* bv   = (const float*)d_in[7];
  const float* Wo   = (const float*)d_in[8];
  const float* bo   = (const float*)d_in[9];
  const float* asc  = (const float*)d_in[10];
  float* out = (float*)d_out;

  unsigned short* w   = (unsigned short*)d_ws;
  unsigned short* Xb  = w;
  unsigned short* Wqb = Xb  + XN;   // Wkb = Wqb + WN (contiguous, used by gemm8<0>)
  unsigned short* Wvb = Wqb + 2 * WN;
  unsigned short* Wob = Wvb + WN;
  unsigned short* Qb  = Wob + WN;
  unsigned short* Kbf = Qb  + XN;
  unsigned short* Vt  = Kbf + XN;
  float*          Bias = (float*)(Vt + XN);
  unsigned short* Ctx = Xb;   // alias: X dead after Q/K/Vt GEMMs

  cast5_kernel<<<2048, 256, 0, stream>>>(x, Wq, Wk, Wv, Wo, Xb, mask, Bias);

  gemm8<0><<<256, 512, 0, stream>>>(Xb, Wqb, bq, bk, Qb);    // Q and K
  gemm8<1><<<256, 512, 0, stream>>>(Wvb, Xb, bv, bv, Vt);    // Vt = (X Wv^T)^T

  norm_qk<<<32768, 256, 0, stream>>>(Qb, Kbf, asc);

  attn_kernel<<<dim3(16, 32), 256, 0, stream>>>(Qb, Kbf, Vt, Bias, Ctx);

  gemm8<2><<<256, 512, 0, stream>>>(Ctx, Wob, bo, bo, out);
}